// Round 4
// baseline (3143.775 us; speedup 1.0000x reference)
//
#include <hip/hip_runtime.h>

#define NN 50000
#define EE 800000
#define NEG 0.2f
#define NBLK_SCAN 196   // ceil(NN/256)
#define NB16 3125       // NN/16

__device__ __forceinline__ float leaky(float x) { return x > 0.f ? x : NEG * x; }
__device__ __forceinline__ unsigned bf16r(float x) {
    unsigned u = __float_as_uint(x);
    return (u + 0x7fffu + ((u >> 16) & 1u)) >> 16;
}
__device__ __forceinline__ unsigned pack2(float g, float q) { return bf16r(g) | (bf16r(q) << 16); }
__device__ __forceinline__ float lo16(unsigned p) { return __uint_as_float(p << 16); }
__device__ __forceinline__ float hi16(unsigned p) { return __uint_as_float(p & 0xffff0000u); }
__device__ __forceinline__ float frombf(unsigned short s) { return __uint_as_float(((unsigned)s) << 16); }

// ================= CSR build =================
__global__ void k_deg(const int* __restrict__ dst, int* __restrict__ degcnt) {
    int e = blockIdx.x * 256 + threadIdx.x;
    atomicAdd(&degcnt[dst[e]], 1);
}

__global__ void k_scan_a(const int* __restrict__ degcnt, int* __restrict__ bsums) {
    __shared__ int sm[4];
    int i = blockIdx.x * 256 + threadIdx.x;
    int v = (i < NN) ? degcnt[i] : 0;
    #pragma unroll
    for (int o = 1; o < 64; o <<= 1) v += __shfl_xor(v, o, 64);
    if ((threadIdx.x & 63) == 0) sm[threadIdx.x >> 6] = v;
    __syncthreads();
    if (threadIdx.x == 0) bsums[blockIdx.x] = sm[0] + sm[1] + sm[2] + sm[3];
}

__global__ void k_scan_b(const int* __restrict__ bsums, int* __restrict__ bpre) {
    __shared__ int sm[256];
    int t = threadIdx.x;
    sm[t] = (t < NBLK_SCAN) ? bsums[t] : 0;
    __syncthreads();
    for (int off = 1; off < 256; off <<= 1) {
        int u = (t >= off) ? sm[t - off] : 0;
        __syncthreads();
        sm[t] += u;
        __syncthreads();
    }
    if (t < NBLK_SCAN) bpre[t] = (t == 0) ? 0 : sm[t - 1];
}

__global__ void k_scan_c(const int* __restrict__ degcnt, const int* __restrict__ bpre,
                         int* __restrict__ row_start, int* __restrict__ cursor) {
    __shared__ int sm[256];
    int t = threadIdx.x;
    int i = blockIdx.x * 256 + t;
    int v = (i < NN) ? degcnt[i] : 0;
    sm[t] = v;
    __syncthreads();
    for (int off = 1; off < 256; off <<= 1) {
        int u = (t >= off) ? sm[t - off] : 0;
        __syncthreads();
        sm[t] += u;
        __syncthreads();
    }
    int incl = sm[t];
    if (i < NN) { int rs = bpre[blockIdx.x] + incl - v; row_start[i] = rs; cursor[i] = rs; }
    if (i == NN - 1) row_start[NN] = bpre[blockIdx.x] + incl;
}

__global__ void k_fill(const int* __restrict__ src, const int* __restrict__ dst,
                       int* __restrict__ cursor, int* __restrict__ csr_src) {
    int e = blockIdx.x * 256 + threadIdx.x;
    int d = dst[e];
    int pos = atomicAdd(&cursor[d], 1);
    csr_src[pos] = src[e];
}

// ================= fused projection + GAT-l0 pre, GEMV-4 per wave =================
__global__ void k_pre(const float* __restrict__ feat, const int* __restrict__ types,
                      const float* __restrict__ Wp, const float* __restrict__ bp,
                      const float* __restrict__ Wd, const float* __restrict__ bd,
                      const float* __restrict__ gW, const float* __restrict__ al,
                      const float* __restrict__ ar,
                      float* __restrict__ h0, unsigned* __restrict__ P0,
                      float* __restrict__ el0, float* __restrict__ er0) {
    int wv = threadIdx.x >> 6, lane = threadIdx.x & 63;
    int nbase = (blockIdx.x * 4 + wv) * 4;
    float xa[4], xb[4], acc[4];
    int t[4];
    #pragma unroll
    for (int i = 0; i < 4; i++) {
        int n = nbase + i;
        xa[i] = feat[(size_t)n * 128 + lane];
        xb[i] = feat[(size_t)n * 128 + 64 + lane];
        t[i] = types[n];
        if (t[i]) xb[i] = 0.f;
        acc[i] = t[i] ? bd[lane] : bp[lane];
    }
    #pragma unroll 4
    for (int k = 0; k < 64; k++) {
        float wp = Wp[k * 64 + lane], wd = Wd[k * 64 + lane];
        #pragma unroll
        for (int i = 0; i < 4; i++) acc[i] += __shfl(xa[i], k, 64) * (t[i] ? wd : wp);
    }
    #pragma unroll 4
    for (int k = 0; k < 64; k++) {
        float wp = Wp[(64 + k) * 64 + lane];
        #pragma unroll
        for (int i = 0; i < 4; i++) acc[i] += __shfl(xb[i], k, 64) * wp;
    }
    float hw[4] = {0, 0, 0, 0};
    #pragma unroll 4
    for (int k = 0; k < 64; k++) {
        float w = gW[k * 64 + lane];
        #pragma unroll
        for (int i = 0; i < 4; i++) hw[i] += __shfl(acc[i], k, 64) * w;
    }
    float alv = al[lane], arv = ar[lane];
    #pragma unroll
    for (int i = 0; i < 4; i++) {
        int n = nbase + i;
        h0[(size_t)n * 64 + lane] = acc[i];
        P0[(size_t)n * 64 + lane] = pack2(hw[i], acc[i]);
        float pl = hw[i] * alv, pr = hw[i] * arv;
        #pragma unroll
        for (int m = 1; m < 16; m <<= 1) { pl += __shfl_xor(pl, m, 16); pr += __shfl_xor(pr, m, 16); }
        if ((lane & 15) == 0) {
            el0[n * 4 + (lane >> 4)] = pl;
            er0[n * 4 + (lane >> 4)] = pr;
        }
    }
}

// ================= fused layer: edges + GIN MLP + (mode0: next-layer GAT pre | mode1: MoE routing) ====
template <int MODE>
__global__ void k_layer(const int* __restrict__ rows, const int* __restrict__ csr,
                        const unsigned* __restrict__ Pin,
                        const float* __restrict__ el, const float* __restrict__ er,
                        const float* __restrict__ gat_in, const float* __restrict__ gin_in,
                        const float* __restrict__ eps_p,
                        const float* __restrict__ W1, const float* __restrict__ b1,
                        const float* __restrict__ W2, const float* __restrict__ b2,
                        float* __restrict__ gat_out, float* __restrict__ gin_out,
                        const float* __restrict__ gW2, const float* __restrict__ al2,
                        const float* __restrict__ ar2,
                        float* __restrict__ el1, float* __restrict__ er1,
                        unsigned* __restrict__ Pout,
                        const float* __restrict__ ggW, const float* __restrict__ ggb,
                        const float* __restrict__ igW, const float* __restrict__ igb,
                        unsigned* __restrict__ aidx, float* __restrict__ awt,
                        int* __restrict__ cnt, float* __restrict__ stats) {
    __shared__ float ews[4][256];
    int wv = threadIdx.x >> 6, lane = threadIdx.x & 63;
    int nbase = (blockIdx.x * 4 + wv) * 4;
    int hd = lane >> 4;
    float eps = eps_p[0];
    float vg[4], x[4];
    // ---- edge phase, node-sequential within wave ----
    #pragma unroll
    for (int i = 0; i < 4; i++) {
        int n = nbase + i;
        int st = rows[n], dg = rows[n + 1] - st;
        float4 erv = *reinterpret_cast<const float4*>(er + (size_t)n * 4);
        float accg = 0.f, acci = 0.f, ssum = 0.f;
        for (int base = 0; base < dg; base += 64) {
            int rem = dg - base; if (rem > 64) rem = 64;
            int myi = 0;
            if (lane < rem) {
                myi = csr[st + base + lane];
                float4 lv = *reinterpret_cast<const float4*>(el + (size_t)myi * 4);
                float4 ev;
                ev.x = __expf(leaky(lv.x + erv.x));
                ev.y = __expf(leaky(lv.y + erv.y));
                ev.z = __expf(leaky(lv.z + erv.z));
                ev.w = __expf(leaky(lv.w + erv.w));
                *reinterpret_cast<float4*>(&ews[wv][lane * 4]) = ev;
            }
            int j = 0;
            for (; j + 4 <= rem; j += 4) {
                int s0 = __shfl(myi, j, 64),     s1 = __shfl(myi, j + 1, 64);
                int s2 = __shfl(myi, j + 2, 64), s3 = __shfl(myi, j + 3, 64);
                unsigned p0 = Pin[(size_t)s0 * 64 + lane];
                unsigned p1 = Pin[(size_t)s1 * 64 + lane];
                unsigned p2 = Pin[(size_t)s2 * 64 + lane];
                unsigned p3 = Pin[(size_t)s3 * 64 + lane];
                float a0 = ews[wv][(j + 0) * 4 + hd];
                float a1 = ews[wv][(j + 1) * 4 + hd];
                float a2 = ews[wv][(j + 2) * 4 + hd];
                float a3 = ews[wv][(j + 3) * 4 + hd];
                accg += a0 * lo16(p0) + a1 * lo16(p1) + a2 * lo16(p2) + a3 * lo16(p3);
                acci += hi16(p0) + hi16(p1) + hi16(p2) + hi16(p3);
                ssum += a0 + a1 + a2 + a3;
            }
            for (; j < rem; j++) {
                int s0 = __shfl(myi, j, 64);
                unsigned p0 = Pin[(size_t)s0 * 64 + lane];
                float a0 = ews[wv][j * 4 + hd];
                accg += a0 * lo16(p0); acci += hi16(p0); ssum += a0;
            }
        }
        vg[i] = accg / (ssum + 1e-9f) + gat_in[(size_t)n * 64 + lane];
        if (MODE == 0) vg[i] = fmaxf(vg[i], 0.f);
        float self;
        if (MODE == 0) self = gin_in[(size_t)n * 64 + lane];
        else           self = hi16(Pin[(size_t)n * 64 + lane]);
        float invd = 1.0f / fmaxf((float)dg, 1.0f);
        x[i] = (1.0f + eps) * self + acci * invd;
    }
    // ---- GIN MLP (GEMV-4, shared weight loads) ----
    float y1[4], y2[4];
    #pragma unroll
    for (int i = 0; i < 4; i++) y1[i] = b1[lane];
    #pragma unroll 4
    for (int k = 0; k < 64; k++) {
        float w = W1[k * 64 + lane];
        #pragma unroll
        for (int i = 0; i < 4; i++) y1[i] += __shfl(x[i], k, 64) * w;
    }
    #pragma unroll
    for (int i = 0; i < 4; i++) { y1[i] = fmaxf(y1[i], 0.f); y2[i] = b2[lane]; }
    #pragma unroll 4
    for (int k = 0; k < 64; k++) {
        float w = W2[k * 64 + lane];
        #pragma unroll
        for (int i = 0; i < 4; i++) y2[i] += __shfl(y1[i], k, 64) * w;
    }
    #pragma unroll
    for (int i = 0; i < 4; i++) {
        if (MODE == 0) y2[i] = fmaxf(y2[i], 0.f);
        gat_out[(size_t)(nbase + i) * 64 + lane] = vg[i];
        gin_out[(size_t)(nbase + i) * 64 + lane] = y2[i];
    }

    if (MODE == 0) {
        // ---- next-layer GAT pre: hW2 = vg @ W2gat, el1/er1, pack ----
        float hw[4] = {0, 0, 0, 0};
        #pragma unroll 4
        for (int k = 0; k < 64; k++) {
            float w = gW2[k * 64 + lane];
            #pragma unroll
            for (int i = 0; i < 4; i++) hw[i] += __shfl(vg[i], k, 64) * w;
        }
        float alv = al2[lane], arv = ar2[lane];
        #pragma unroll
        for (int i = 0; i < 4; i++) {
            int n = nbase + i;
            Pout[(size_t)n * 64 + lane] = pack2(hw[i], y2[i]);
            float pl = hw[i] * alv, pr = hw[i] * arv;
            #pragma unroll
            for (int m = 1; m < 16; m <<= 1) { pl += __shfl_xor(pl, m, 16); pr += __shfl_xor(pr, m, 16); }
            if ((lane & 15) == 0) {
                el1[n * 4 + (lane >> 4)] = pl;
                er1[n * 4 + (lane >> 4)] = pr;
            }
        }
    } else {
        // ---- MoE routing for both problems ----
        float4 gw_g = *reinterpret_cast<const float4*>(ggW + lane * 4);
        float4 gw_i = *reinterpret_cast<const float4*>(igW + lane * 4);
        float sp[2][4] = {{0, 0, 0, 0}, {0, 0, 0, 0}};
        float sh[2][4] = {{0, 0, 0, 0}, {0, 0, 0, 0}};
        for (int q = 0; q < 2; q++) {
            float4 gw = q ? gw_i : gw_g;
            const float* gb = q ? igb : ggb;
            float g0 = gb[0], g1 = gb[1], g2 = gb[2], g3 = gb[3];
            #pragma unroll
            for (int i = 0; i < 4; i++) {
                float v = q ? y2[i] : vg[i];
                float p0 = v * gw.x, p1 = v * gw.y, p2 = v * gw.z, p3 = v * gw.w;
                #pragma unroll
                for (int m = 1; m < 64; m <<= 1) {
                    p0 += __shfl_xor(p0, m, 64); p1 += __shfl_xor(p1, m, 64);
                    p2 += __shfl_xor(p2, m, 64); p3 += __shfl_xor(p3, m, 64);
                }
                p0 += g0; p1 += g1; p2 += g2; p3 += g3;
                float mx = fmaxf(fmaxf(p0, p1), fmaxf(p2, p3));
                float e0 = __expf(p0 - mx), e1 = __expf(p1 - mx);
                float e2 = __expf(p2 - mx), e3 = __expf(p3 - mx);
                float inv = 1.0f / (e0 + e1 + e2 + e3);
                float pr[4] = {e0 * inv, e1 * inv, e2 * inv, e3 * inv};
                int i1 = 0; float v1 = pr[0];
                #pragma unroll
                for (int e = 1; e < 4; e++) if (pr[e] > v1) { v1 = pr[e]; i1 = e; }
                int i2 = -1; float v2 = -1.f;
                #pragma unroll
                for (int e = 0; e < 4; e++) if (e != i1 && pr[e] > v2) { v2 = pr[e]; i2 = e; }
                float wsum = v1 + v2;
                float w0 = v1 / wsum, w1 = v2 / wsum;
                #pragma unroll
                for (int e = 0; e < 4; e++) sp[q][e] += pr[e];
                sh[q][i1] += 1.f; sh[q][i2] += 1.f;
                if (lane == 0) {
                    int n = nbase + i;
                    int bkt = q * 4 + i1;
                    int pos = atomicAdd(&cnt[bkt], 1);
                    aidx[(size_t)bkt * NN + pos] = (unsigned)n;
                    awt[(size_t)bkt * NN + pos] = w0;
                    bkt = q * 4 + i2;
                    pos = atomicAdd(&cnt[bkt], 1);
                    aidx[(size_t)bkt * NN + pos] = (unsigned)n | 0x80000000u;
                    awt[(size_t)bkt * NN + pos] = w1;
                }
            }
        }
        if (lane == 0) {
            int sl = (blockIdx.x * 4 + wv) & 63;
            #pragma unroll
            for (int q = 0; q < 2; q++)
                #pragma unroll
                for (int e = 0; e < 4; e++) {
                    atomicAdd(&stats[sl * 16 + q * 8 + e], sp[q][e]);
                    atomicAdd(&stats[sl * 16 + q * 8 + 4 + e], sh[q][e]);
                }
        }
    }
}

// ================= expert-grouped MoE MLPs (GEMV-4, shared weights per bucket) ===========
__global__ void k_expert(const unsigned* __restrict__ aidx, const float* __restrict__ awt,
                         const int* __restrict__ cnt,
                         const float* __restrict__ zgat, const float* __restrict__ zgin,
                         const float* __restrict__ gat_eW1, const float* __restrict__ gat_eb1,
                         const float* __restrict__ gat_eW2, const float* __restrict__ gat_eb2,
                         const float* __restrict__ gin_eW1, const float* __restrict__ gin_eb1,
                         const float* __restrict__ gin_eW2, const float* __restrict__ gin_eb2,
                         unsigned short* __restrict__ r0g, unsigned short* __restrict__ r1g,
                         unsigned short* __restrict__ r0i, unsigned short* __restrict__ r1i) {
    int wv = threadIdx.x >> 6, lane = threadIdx.x & 63;
    int W = blockIdx.x * 4 + wv;               // global wave id
    int pe = W / 12500;                         // bucket (p*4+e)
    int loc = (W - pe * 12500) * 4;
    int c = cnt[pe];
    if (loc >= c) return;
    int p = pe >> 2, e = pe & 3;
    const float* X  = p ? zgin : zgat;
    const float* w1 = (p ? gin_eW1 : gat_eW1) + (size_t)e * 2048;
    const float* bb1 = (p ? gin_eb1 : gat_eb1) + e * 32;
    const float* w2 = (p ? gin_eW2 : gat_eW2) + (size_t)e * 2048;
    const float* bb2 = (p ? gin_eb2 : gat_eb2) + e * 64;
    unsigned short* R0 = p ? r0i : r0g;
    unsigned short* R1 = p ? r1i : r1g;
    int m = c - loc; if (m > 4) m = 4;
    int na[4]; float wt[4]; int rk[4];
    #pragma unroll
    for (int i = 0; i < 4; i++) {
        int idx = loc + (i < m ? i : 0);
        unsigned a = aidx[(size_t)pe * NN + idx];
        na[i] = (int)(a & 0x7fffffffu);
        rk[i] = (int)(a >> 31);
        wt[i] = awt[(size_t)pe * NN + idx];
    }
    float xr[4], y1[4], y2[4];
    int j = lane & 31;
    #pragma unroll
    for (int i = 0; i < 4; i++) { xr[i] = X[(size_t)na[i] * 64 + lane]; y1[i] = bb1[j]; }
    #pragma unroll 4
    for (int k = 0; k < 64; k++) {
        float w = w1[k * 32 + j];
        #pragma unroll
        for (int i = 0; i < 4; i++) y1[i] += __shfl(xr[i], k, 64) * w;
    }
    #pragma unroll
    for (int i = 0; i < 4; i++) { y1[i] = fmaxf(y1[i], 0.f); y2[i] = bb2[lane]; }
    #pragma unroll 4
    for (int k = 0; k < 32; k++) {
        float w = w2[k * 64 + lane];
        #pragma unroll
        for (int i = 0; i < 4; i++) y2[i] += __shfl(y1[i], k, 64) * w;
    }
    #pragma unroll
    for (int i = 0; i < 4; i++) {
        if (i < m) {
            unsigned short v = (unsigned short)bf16r(wt[i] * y2[i]);
            unsigned short* R = rk[i] ? R1 : R0;
            R[(size_t)na[i] * 64 + lane] = v;
        }
    }
}

// ================= fusion gate (GEMV-4) =================
__global__ void k_fusion(const unsigned short* __restrict__ r0g, const unsigned short* __restrict__ r1g,
                         const unsigned short* __restrict__ r0i, const unsigned short* __restrict__ r1i,
                         const float* __restrict__ W1, const float* __restrict__ b1,
                         const float* __restrict__ W2, const float* __restrict__ b2,
                         float* __restrict__ out) {
    int wv = threadIdx.x >> 6, lane = threadIdx.x & 63;
    int nbase = (blockIdx.x * 4 + wv) * 4;
    float zg[4], zi[4], a1[4], g[4];
    #pragma unroll
    for (int i = 0; i < 4; i++) {
        size_t off = (size_t)(nbase + i) * 64 + lane;
        zg[i] = frombf(r0g[off]) + frombf(r1g[off]);
        zi[i] = frombf(r0i[off]) + frombf(r1i[off]);
        a1[i] = b1[lane];
    }
    #pragma unroll 4
    for (int k = 0; k < 64; k++) {
        float w = W1[k * 64 + lane];
        #pragma unroll
        for (int i = 0; i < 4; i++) a1[i] += __shfl(zg[i], k, 64) * w;
    }
    #pragma unroll 4
    for (int k = 0; k < 64; k++) {
        float w = W1[(64 + k) * 64 + lane];
        #pragma unroll
        for (int i = 0; i < 4; i++) a1[i] += __shfl(zi[i], k, 64) * w;
    }
    #pragma unroll
    for (int i = 0; i < 4; i++) { a1[i] = fmaxf(a1[i], 0.f); g[i] = b2[lane]; }
    #pragma unroll 4
    for (int k = 0; k < 64; k++) {
        float w = W2[k * 64 + lane];
        #pragma unroll
        for (int i = 0; i < 4; i++) g[i] += __shfl(a1[i], k, 64) * w;
    }
    #pragma unroll
    for (int i = 0; i < 4; i++) {
        float gg = 1.0f / (1.0f + __expf(-g[i]));
        float zv = zg[i] * zi[i];
        out[(size_t)(nbase + i) * 64 + lane] = gg * zv + (1.0f - gg) * gg;
    }
}

// ================= aux finalize (one wave) =================
__global__ void k_finalize(const float* __restrict__ stats, float* __restrict__ outAux) {
    int t = threadIdx.x;
    float s = 0.f;
    if (t < 16)
        for (int k = 0; k < 64; k++) s += stats[k * 16 + t];
    float aux = 0.f;
    for (int q = 0; q < 2; q++) {
        float a = 0.f;
        for (int e = 0; e < 4; e++) {
            float pr = __shfl(s, q * 8 + e, 64);
            float f  = __shfl(s, q * 8 + 4 + e, 64);
            a += (f / (float)NN) * (pr / (float)NN);
        }
        aux += 4.0f * a;
    }
    if (t == 0) *outAux = aux;
}

extern "C" void kernel_launch(void* const* d_in, const int* in_sizes, int n_in,
                              void* d_out, int out_size, void* d_ws, size_t ws_size,
                              hipStream_t stream) {
    (void)in_sizes; (void)n_in; (void)out_size; (void)ws_size;
    const float* features  = (const float*)d_in[0];
    const int*   node_types= (const int*)d_in[1];
    const int*   src       = (const int*)d_in[2];
    const int*   dst       = (const int*)d_in[3];
    const float* W_person  = (const float*)d_in[4];
    const float* b_person  = (const float*)d_in[5];
    const float* W_disease = (const float*)d_in[6];
    const float* b_disease = (const float*)d_in[7];
    const float* gat_W     = (const float*)d_in[8];
    const float* gat_al    = (const float*)d_in[9];
    const float* gat_ar    = (const float*)d_in[10];
    const float* gin_eps   = (const float*)d_in[11];
    const float* gin_W1    = (const float*)d_in[12];
    const float* gin_b1    = (const float*)d_in[13];
    const float* gin_W2    = (const float*)d_in[14];
    const float* gin_b2    = (const float*)d_in[15];
    const float* gat_gW    = (const float*)d_in[16];
    const float* gat_gb    = (const float*)d_in[17];
    const float* gat_eW1   = (const float*)d_in[18];
    const float* gat_eb1   = (const float*)d_in[19];
    const float* gat_eW2   = (const float*)d_in[20];
    const float* gat_eb2   = (const float*)d_in[21];
    const float* gin_gW    = (const float*)d_in[22];
    const float* gin_gb    = (const float*)d_in[23];
    const float* gin_eW1   = (const float*)d_in[24];
    const float* gin_eb1   = (const float*)d_in[25];
    const float* gin_eW2   = (const float*)d_in[26];
    const float* gin_eb2   = (const float*)d_in[27];
    const float* fg_W1     = (const float*)d_in[28];
    const float* fg_b1     = (const float*)d_in[29];
    const float* fg_W2     = (const float*)d_in[30];
    const float* fg_b2     = (const float*)d_in[31];
    float* out = (float*)d_out;

    float* ws = (float*)d_ws;
    size_t o = 0;
    float*    A  = ws + o; o += (size_t)NN * 64;   // h0 -> z_gin(final)
    float*    B  = ws + o; o += (size_t)NN * 64;   // GAT chain -> z_gat(final)
    float*    D  = ws + o; o += (size_t)NN * 64;   // gin l0 out; later r0g/r1g (bf16)
    unsigned* P0 = (unsigned*)(ws + o); o += (size_t)NN * 64;  // packed l0; later r0i/r1i
    unsigned* P1 = (unsigned*)(ws + o); o += (size_t)NN * 64;  // packed l1
    float* el0 = ws + o; o += (size_t)NN * 4;
    float* er0 = ws + o; o += (size_t)NN * 4;
    float* el1 = ws + o; o += (size_t)NN * 4;
    float* er1 = ws + o; o += (size_t)NN * 4;
    int*   cnt   = (int*)(ws + o); o += 8;          // cnt + stats: one memset region
    float* stats = ws + o; o += 1024;
    int* degcnt    = (int*)(ws + o); o += NN;
    int* row_start = (int*)(ws + o); o += NN + 4;
    int* cursor    = (int*)(ws + o); o += NN;
    int* bsums     = (int*)(ws + o); o += 256;
    int* bpre      = (int*)(ws + o); o += 256;
    int* csr_src   = (int*)(ws + o); o += EE;
    unsigned* aidx = (unsigned*)(ws + o); o += (size_t)8 * NN;
    float*    awt  = ws + o; o += (size_t)8 * NN;

    unsigned short* r0g = (unsigned short*)D;
    unsigned short* r1g = (unsigned short*)D + (size_t)NN * 64;
    unsigned short* r0i = (unsigned short*)P0;
    unsigned short* r1i = (unsigned short*)P0 + (size_t)NN * 64;

    const int NB_edge = EE / 256;   // 3125

    hipMemsetAsync(degcnt, 0, sizeof(int) * NN, stream);
    hipMemsetAsync(cnt, 0, sizeof(int) * 8 + sizeof(float) * 1024, stream);

    // CSR build
    k_deg<<<NB_edge, 256, 0, stream>>>(dst, degcnt);
    k_scan_a<<<NBLK_SCAN, 256, 0, stream>>>(degcnt, bsums);
    k_scan_b<<<1, 256, 0, stream>>>(bsums, bpre);
    k_scan_c<<<NBLK_SCAN, 256, 0, stream>>>(degcnt, bpre, row_start, cursor);
    k_fill<<<NB_edge, 256, 0, stream>>>(src, dst, cursor, csr_src);

    // projection + GAT-l0 pre
    k_pre<<<NB16, 256, 0, stream>>>(features, node_types, W_person, b_person,
                                    W_disease, b_disease, gat_W, gat_al, gat_ar,
                                    A, P0, el0, er0);

    // layer 0: edges + GIN MLP + next-layer GAT pre
    k_layer<0><<<NB16, 256, 0, stream>>>(row_start, csr_src, P0, el0, er0, A, A, gin_eps,
                                         gin_W1, gin_b1, gin_W2, gin_b2, B, D,
                                         gat_W + 4096, gat_al + 64, gat_ar + 64, el1, er1, P1,
                                         nullptr, nullptr, nullptr, nullptr,
                                         nullptr, nullptr, nullptr, nullptr);
    // layer 1: edges + GIN MLP + MoE routing
    k_layer<1><<<NB16, 256, 0, stream>>>(row_start, csr_src, P1, el1, er1, B, nullptr,
                                         gin_eps + 1, gin_W1 + 4096, gin_b1 + 64,
                                         gin_W2 + 4096, gin_b2 + 64, B, A,
                                         nullptr, nullptr, nullptr, nullptr, nullptr, nullptr,
                                         gat_gW, gat_gb, gin_gW, gin_gb,
                                         aidx, awt, cnt, stats);

    // expert-grouped MoE MLPs (both problems, all experts)
    k_expert<<<25000, 256, 0, stream>>>(aidx, awt, cnt, B, A,
                                        gat_eW1, gat_eb1, gat_eW2, gat_eb2,
                                        gin_eW1, gin_eb1, gin_eW2, gin_eb2,
                                        r0g, r1g, r0i, r1i);

    // fusion + aux
    k_fusion<<<NB16, 256, 0, stream>>>(r0g, r1g, r0i, r1i, fg_W1, fg_b1, fg_W2, fg_b2, out);
    k_finalize<<<1, 64, 0, stream>>>(stats, out + (size_t)NN * 64);
}

// Round 5
// 939.448 us; speedup vs baseline: 3.3464x; 3.3464x over previous
//
#include <hip/hip_runtime.h>

#define NN 50000
#define EE 800000
#define NEG 0.2f
#define NBLK_SCAN 196   // ceil(NN/256)
#define NB16 3125       // NN/16

__device__ __forceinline__ float leaky(float x) { return x > 0.f ? x : NEG * x; }
__device__ __forceinline__ unsigned bf16r(float x) {
    unsigned u = __float_as_uint(x);
    return (u + 0x7fffu + ((u >> 16) & 1u)) >> 16;
}
__device__ __forceinline__ unsigned pack2(float g, float q) { return bf16r(g) | (bf16r(q) << 16); }
__device__ __forceinline__ float lo16(unsigned p) { return __uint_as_float(p << 16); }
__device__ __forceinline__ float hi16(unsigned p) { return __uint_as_float(p & 0xffff0000u); }
__device__ __forceinline__ float frombf(unsigned short s) { return __uint_as_float(((unsigned)s) << 16); }

// ================= CSR build =================
__global__ void k_deg(const int* __restrict__ dst, int* __restrict__ degcnt) {
    int e = blockIdx.x * 256 + threadIdx.x;
    atomicAdd(&degcnt[dst[e]], 1);
}

__global__ void k_scan_a(const int* __restrict__ degcnt, int* __restrict__ bsums) {
    __shared__ int sm[4];
    int i = blockIdx.x * 256 + threadIdx.x;
    int v = (i < NN) ? degcnt[i] : 0;
    #pragma unroll
    for (int o = 1; o < 64; o <<= 1) v += __shfl_xor(v, o, 64);
    if ((threadIdx.x & 63) == 0) sm[threadIdx.x >> 6] = v;
    __syncthreads();
    if (threadIdx.x == 0) bsums[blockIdx.x] = sm[0] + sm[1] + sm[2] + sm[3];
}

__global__ void k_scan_b(const int* __restrict__ bsums, int* __restrict__ bpre) {
    __shared__ int sm[256];
    int t = threadIdx.x;
    sm[t] = (t < NBLK_SCAN) ? bsums[t] : 0;
    __syncthreads();
    for (int off = 1; off < 256; off <<= 1) {
        int u = (t >= off) ? sm[t - off] : 0;
        __syncthreads();
        sm[t] += u;
        __syncthreads();
    }
    if (t < NBLK_SCAN) bpre[t] = (t == 0) ? 0 : sm[t - 1];
}

__global__ void k_scan_c(const int* __restrict__ degcnt, const int* __restrict__ bpre,
                         int* __restrict__ row_start, int* __restrict__ cursor) {
    __shared__ int sm[256];
    int t = threadIdx.x;
    int i = blockIdx.x * 256 + t;
    int v = (i < NN) ? degcnt[i] : 0;
    sm[t] = v;
    __syncthreads();
    for (int off = 1; off < 256; off <<= 1) {
        int u = (t >= off) ? sm[t - off] : 0;
        __syncthreads();
        sm[t] += u;
        __syncthreads();
    }
    int incl = sm[t];
    if (i < NN) { int rs = bpre[blockIdx.x] + incl - v; row_start[i] = rs; cursor[i] = rs; }
    if (i == NN - 1) row_start[NN] = bpre[blockIdx.x] + incl;
}

__global__ void k_fill(const int* __restrict__ src, const int* __restrict__ dst,
                       int* __restrict__ cursor, int* __restrict__ csr_src) {
    int e = blockIdx.x * 256 + threadIdx.x;
    int d = dst[e];
    int pos = atomicAdd(&cursor[d], 1);
    csr_src[pos] = src[e];
}

// ================= fused projection + GAT-l0 pre (GEMV-4) =================
__global__ void k_pre(const float* __restrict__ feat, const int* __restrict__ types,
                      const float* __restrict__ Wp, const float* __restrict__ bp,
                      const float* __restrict__ Wd, const float* __restrict__ bd,
                      const float* __restrict__ gW, const float* __restrict__ al,
                      const float* __restrict__ ar,
                      float* __restrict__ h0, unsigned* __restrict__ P0,
                      float* __restrict__ el0, float* __restrict__ er0) {
    int wv = threadIdx.x >> 6, lane = threadIdx.x & 63;
    int nbase = (blockIdx.x * 4 + wv) * 4;
    float xa[4], xb[4], acc[4];
    int t[4];
    #pragma unroll
    for (int i = 0; i < 4; i++) {
        int n = nbase + i;
        xa[i] = feat[(size_t)n * 128 + lane];
        xb[i] = feat[(size_t)n * 128 + 64 + lane];
        t[i] = types[n];
        if (t[i]) xb[i] = 0.f;
        acc[i] = t[i] ? bd[lane] : bp[lane];
    }
    #pragma unroll 4
    for (int k = 0; k < 64; k++) {
        float wp = Wp[k * 64 + lane], wd = Wd[k * 64 + lane];
        #pragma unroll
        for (int i = 0; i < 4; i++) acc[i] += __shfl(xa[i], k, 64) * (t[i] ? wd : wp);
    }
    #pragma unroll 4
    for (int k = 0; k < 64; k++) {
        float wp = Wp[(64 + k) * 64 + lane];
        #pragma unroll
        for (int i = 0; i < 4; i++) acc[i] += __shfl(xb[i], k, 64) * wp;
    }
    float hw[4] = {0, 0, 0, 0};
    #pragma unroll 4
    for (int k = 0; k < 64; k++) {
        float w = gW[k * 64 + lane];
        #pragma unroll
        for (int i = 0; i < 4; i++) hw[i] += __shfl(acc[i], k, 64) * w;
    }
    float alv = al[lane], arv = ar[lane];
    #pragma unroll
    for (int i = 0; i < 4; i++) {
        int n = nbase + i;
        h0[(size_t)n * 64 + lane] = acc[i];
        P0[(size_t)n * 64 + lane] = pack2(hw[i], acc[i]);
        float pl = hw[i] * alv, pr = hw[i] * arv;
        #pragma unroll
        for (int m = 1; m < 16; m <<= 1) { pl += __shfl_xor(pl, m, 16); pr += __shfl_xor(pr, m, 16); }
        if ((lane & 15) == 0) {
            el0[n * 4 + (lane >> 4)] = pl;
            er0[n * 4 + (lane >> 4)] = pr;
        }
    }
}

// ================= edge walk: 1 node per wave, exp once/edge, packed bf16 gather ======
template <int RELU>
__global__ void k_edges(const int* __restrict__ rows, const int* __restrict__ csr,
                        const unsigned* __restrict__ Pin,
                        const float* __restrict__ el, const float* __restrict__ er,
                        const float* __restrict__ gat_in, const float* __restrict__ gin_in,
                        const float* __restrict__ eps_p,
                        float* __restrict__ vg_out, float* __restrict__ x_out) {
    __shared__ float ews[4][256];
    int wv = threadIdx.x >> 6, lane = threadIdx.x & 63;
    int n = blockIdx.x * 4 + wv;
    int st = rows[n], dg = rows[n + 1] - st;
    int hd = lane >> 4;
    float4 erv = *reinterpret_cast<const float4*>(er + (size_t)n * 4);
    float accg = 0.f, acci = 0.f, ssum = 0.f;
    for (int base = 0; base < dg; base += 64) {
        int rem = dg - base; if (rem > 64) rem = 64;
        int myi = 0;
        if (lane < rem) {
            myi = csr[st + base + lane];
            float4 lv = *reinterpret_cast<const float4*>(el + (size_t)myi * 4);
            float4 ev;
            ev.x = __expf(leaky(lv.x + erv.x));
            ev.y = __expf(leaky(lv.y + erv.y));
            ev.z = __expf(leaky(lv.z + erv.z));
            ev.w = __expf(leaky(lv.w + erv.w));
            *reinterpret_cast<float4*>(&ews[wv][lane * 4]) = ev;
        }
        int j = 0;
        for (; j + 4 <= rem; j += 4) {
            int s0 = __shfl(myi, j, 64),     s1 = __shfl(myi, j + 1, 64);
            int s2 = __shfl(myi, j + 2, 64), s3 = __shfl(myi, j + 3, 64);
            unsigned p0 = Pin[(size_t)s0 * 64 + lane];
            unsigned p1 = Pin[(size_t)s1 * 64 + lane];
            unsigned p2 = Pin[(size_t)s2 * 64 + lane];
            unsigned p3 = Pin[(size_t)s3 * 64 + lane];
            float a0 = ews[wv][(j + 0) * 4 + hd];
            float a1 = ews[wv][(j + 1) * 4 + hd];
            float a2 = ews[wv][(j + 2) * 4 + hd];
            float a3 = ews[wv][(j + 3) * 4 + hd];
            accg += a0 * lo16(p0) + a1 * lo16(p1) + a2 * lo16(p2) + a3 * lo16(p3);
            acci += hi16(p0) + hi16(p1) + hi16(p2) + hi16(p3);
            ssum += a0 + a1 + a2 + a3;
        }
        for (; j < rem; j++) {
            int s0 = __shfl(myi, j, 64);
            unsigned p0 = Pin[(size_t)s0 * 64 + lane];
            float a0 = ews[wv][j * 4 + hd];
            accg += a0 * lo16(p0); acci += hi16(p0); ssum += a0;
        }
    }
    float vg = accg / (ssum + 1e-9f) + gat_in[(size_t)n * 64 + lane];
    if (RELU) vg = fmaxf(vg, 0.f);
    float invd = 1.0f / fmaxf((float)dg, 1.0f);
    float x = (1.0f + eps_p[0]) * gin_in[(size_t)n * 64 + lane] + acci * invd;
    vg_out[(size_t)n * 64 + lane] = vg;
    x_out[(size_t)n * 64 + lane] = x;
}

// ================= dense per-layer tail: GIN MLP + (MODE0: next GAT pre | MODE1: routing) ==
template <int MODE>
__global__ void k_dense(const float* __restrict__ X, const float* __restrict__ VG,
                        const float* __restrict__ W1, const float* __restrict__ b1,
                        const float* __restrict__ W2, const float* __restrict__ b2,
                        float* __restrict__ gin_out,
                        const float* __restrict__ gW2, const float* __restrict__ al2,
                        const float* __restrict__ ar2,
                        unsigned* __restrict__ Pout, float* __restrict__ el1,
                        float* __restrict__ er1,
                        const float* __restrict__ ggW, const float* __restrict__ ggb,
                        const float* __restrict__ igW, const float* __restrict__ igb,
                        unsigned* __restrict__ aidx, float* __restrict__ awt,
                        int* __restrict__ cnt, float* __restrict__ stats) {
    __shared__ int lcnt[8];
    __shared__ int lbase[8];
    __shared__ unsigned sidx[8][16];
    __shared__ float swt[8][16];
    __shared__ float sstat[16];
    int wv = threadIdx.x >> 6, lane = threadIdx.x & 63;
    int nbase = (blockIdx.x * 4 + wv) * 4;
    if (MODE == 1) {
        if (threadIdx.x < 8) lcnt[threadIdx.x] = 0;
        if (threadIdx.x < 16) sstat[threadIdx.x] = 0.f;
        __syncthreads();
    }
    float x[4], vg[4], y1[4], y2[4];
    #pragma unroll
    for (int i = 0; i < 4; i++) {
        size_t off = (size_t)(nbase + i) * 64 + lane;
        x[i] = X[off];
        vg[i] = VG[off];
        y1[i] = b1[lane];
    }
    #pragma unroll 4
    for (int k = 0; k < 64; k++) {
        float w = W1[k * 64 + lane];
        #pragma unroll
        for (int i = 0; i < 4; i++) y1[i] += __shfl(x[i], k, 64) * w;
    }
    #pragma unroll
    for (int i = 0; i < 4; i++) { y1[i] = fmaxf(y1[i], 0.f); y2[i] = b2[lane]; }
    #pragma unroll 4
    for (int k = 0; k < 64; k++) {
        float w = W2[k * 64 + lane];
        #pragma unroll
        for (int i = 0; i < 4; i++) y2[i] += __shfl(y1[i], k, 64) * w;
    }
    #pragma unroll
    for (int i = 0; i < 4; i++) {
        if (MODE == 0) y2[i] = fmaxf(y2[i], 0.f);
        gin_out[(size_t)(nbase + i) * 64 + lane] = y2[i];
    }

    if (MODE == 0) {
        // next-layer GAT pre from vg
        float hw[4] = {0, 0, 0, 0};
        #pragma unroll 4
        for (int k = 0; k < 64; k++) {
            float w = gW2[k * 64 + lane];
            #pragma unroll
            for (int i = 0; i < 4; i++) hw[i] += __shfl(vg[i], k, 64) * w;
        }
        float alv = al2[lane], arv = ar2[lane];
        #pragma unroll
        for (int i = 0; i < 4; i++) {
            int n = nbase + i;
            Pout[(size_t)n * 64 + lane] = pack2(hw[i], y2[i]);
            float pl = hw[i] * alv, pr = hw[i] * arv;
            #pragma unroll
            for (int m = 1; m < 16; m <<= 1) { pl += __shfl_xor(pl, m, 16); pr += __shfl_xor(pr, m, 16); }
            if ((lane & 15) == 0) {
                el1[n * 4 + (lane >> 4)] = pl;
                er1[n * 4 + (lane >> 4)] = pr;
            }
        }
    } else {
        // MoE routing, hierarchical (LDS staging, 8 global atomics per block)
        float4 gw_g = *reinterpret_cast<const float4*>(ggW + lane * 4);
        float4 gw_i = *reinterpret_cast<const float4*>(igW + lane * 4);
        float sp[2][4] = {{0, 0, 0, 0}, {0, 0, 0, 0}};
        float sh[2][4] = {{0, 0, 0, 0}, {0, 0, 0, 0}};
        for (int q = 0; q < 2; q++) {
            float4 gw = q ? gw_i : gw_g;
            const float* gb = q ? igb : ggb;
            float g0 = gb[0], g1 = gb[1], g2 = gb[2], g3 = gb[3];
            #pragma unroll
            for (int i = 0; i < 4; i++) {
                float v = q ? y2[i] : vg[i];
                float p0 = v * gw.x, p1 = v * gw.y, p2 = v * gw.z, p3 = v * gw.w;
                #pragma unroll
                for (int m = 1; m < 64; m <<= 1) {
                    p0 += __shfl_xor(p0, m, 64); p1 += __shfl_xor(p1, m, 64);
                    p2 += __shfl_xor(p2, m, 64); p3 += __shfl_xor(p3, m, 64);
                }
                p0 += g0; p1 += g1; p2 += g2; p3 += g3;
                float mx = fmaxf(fmaxf(p0, p1), fmaxf(p2, p3));
                float e0 = __expf(p0 - mx), e1 = __expf(p1 - mx);
                float e2 = __expf(p2 - mx), e3 = __expf(p3 - mx);
                float inv = 1.0f / (e0 + e1 + e2 + e3);
                float pr[4] = {e0 * inv, e1 * inv, e2 * inv, e3 * inv};
                int i1 = 0; float v1 = pr[0];
                #pragma unroll
                for (int e = 1; e < 4; e++) if (pr[e] > v1) { v1 = pr[e]; i1 = e; }
                int i2 = -1; float v2 = -1.f;
                #pragma unroll
                for (int e = 0; e < 4; e++) if (e != i1 && pr[e] > v2) { v2 = pr[e]; i2 = e; }
                float wsum = v1 + v2;
                float w0 = v1 / wsum, w1 = v2 / wsum;
                #pragma unroll
                for (int e = 0; e < 4; e++) sp[q][e] += pr[e];
                sh[q][i1] += 1.f; sh[q][i2] += 1.f;
                if (lane == 0) {
                    int n = nbase + i;
                    int b0 = q * 4 + i1;
                    int pos = atomicAdd(&lcnt[b0], 1);
                    sidx[b0][pos] = (unsigned)n;
                    swt[b0][pos] = w0;
                    int b1v = q * 4 + i2;
                    pos = atomicAdd(&lcnt[b1v], 1);
                    sidx[b1v][pos] = (unsigned)n | 0x80000000u;
                    swt[b1v][pos] = w1;
                }
            }
        }
        if (lane == 0) {
            #pragma unroll
            for (int q = 0; q < 2; q++)
                #pragma unroll
                for (int e = 0; e < 4; e++) {
                    atomicAdd(&sstat[q * 8 + e], sp[q][e]);
                    atomicAdd(&sstat[q * 8 + 4 + e], sh[q][e]);
                }
        }
        __syncthreads();
        if (threadIdx.x < 8)
            lbase[threadIdx.x] = atomicAdd(&cnt[threadIdx.x], lcnt[threadIdx.x]);
        if (threadIdx.x >= 32 && threadIdx.x < 48) {
            int t = threadIdx.x - 32;
            atomicAdd(&stats[t], sstat[t]);
        }
        __syncthreads();
        int b = threadIdx.x >> 5, ii = threadIdx.x & 31;
        if (ii < lcnt[b]) {
            aidx[(size_t)b * NN + lbase[b] + ii] = sidx[b][ii];
            awt[(size_t)b * NN + lbase[b] + ii] = swt[b][ii];
        }
    }
}

// ================= expert-grouped MoE MLPs (GEMV-4) =================
__global__ void k_expert(const unsigned* __restrict__ aidx, const float* __restrict__ awt,
                         const int* __restrict__ cnt,
                         const float* __restrict__ zgat, const float* __restrict__ zgin,
                         const float* __restrict__ gat_eW1, const float* __restrict__ gat_eb1,
                         const float* __restrict__ gat_eW2, const float* __restrict__ gat_eb2,
                         const float* __restrict__ gin_eW1, const float* __restrict__ gin_eb1,
                         const float* __restrict__ gin_eW2, const float* __restrict__ gin_eb2,
                         unsigned short* __restrict__ r0g, unsigned short* __restrict__ r1g,
                         unsigned short* __restrict__ r0i, unsigned short* __restrict__ r1i) {
    int wv = threadIdx.x >> 6, lane = threadIdx.x & 63;
    int W = blockIdx.x * 4 + wv;
    int pe = W / 12500;
    int loc = (W - pe * 12500) * 4;
    int c = cnt[pe];
    if (loc >= c) return;
    int p = pe >> 2, e = pe & 3;
    const float* X  = p ? zgin : zgat;
    const float* w1 = (p ? gin_eW1 : gat_eW1) + (size_t)e * 2048;
    const float* bb1 = (p ? gin_eb1 : gat_eb1) + e * 32;
    const float* w2 = (p ? gin_eW2 : gat_eW2) + (size_t)e * 2048;
    const float* bb2 = (p ? gin_eb2 : gat_eb2) + e * 64;
    unsigned short* R0 = p ? r0i : r0g;
    unsigned short* R1 = p ? r1i : r1g;
    int m = c - loc; if (m > 4) m = 4;
    int na[4]; float wt[4]; int rk[4];
    #pragma unroll
    for (int i = 0; i < 4; i++) {
        int idx = loc + (i < m ? i : 0);
        unsigned a = aidx[(size_t)pe * NN + idx];
        na[i] = (int)(a & 0x7fffffffu);
        rk[i] = (int)(a >> 31);
        wt[i] = awt[(size_t)pe * NN + idx];
    }
    float xr[4], y1[4], y2[4];
    int j = lane & 31;
    #pragma unroll
    for (int i = 0; i < 4; i++) { xr[i] = X[(size_t)na[i] * 64 + lane]; y1[i] = bb1[j]; }
    #pragma unroll 4
    for (int k = 0; k < 64; k++) {
        float w = w1[k * 32 + j];
        #pragma unroll
        for (int i = 0; i < 4; i++) y1[i] += __shfl(xr[i], k, 64) * w;
    }
    #pragma unroll
    for (int i = 0; i < 4; i++) { y1[i] = fmaxf(y1[i], 0.f); y2[i] = bb2[lane]; }
    #pragma unroll 4
    for (int k = 0; k < 32; k++) {
        float w = w2[k * 64 + lane];
        #pragma unroll
        for (int i = 0; i < 4; i++) y2[i] += __shfl(y1[i], k, 64) * w;
    }
    #pragma unroll
    for (int i = 0; i < 4; i++) {
        if (i < m) {
            unsigned short v = (unsigned short)bf16r(wt[i] * y2[i]);
            unsigned short* R = rk[i] ? R1 : R0;
            R[(size_t)na[i] * 64 + lane] = v;
        }
    }
}

// ================= fusion gate (GEMV-4) =================
__global__ void k_fusion(const unsigned short* __restrict__ r0g, const unsigned short* __restrict__ r1g,
                         const unsigned short* __restrict__ r0i, const unsigned short* __restrict__ r1i,
                         const float* __restrict__ W1, const float* __restrict__ b1,
                         const float* __restrict__ W2, const float* __restrict__ b2,
                         float* __restrict__ out) {
    int wv = threadIdx.x >> 6, lane = threadIdx.x & 63;
    int nbase = (blockIdx.x * 4 + wv) * 4;
    float zg[4], zi[4], a1[4], g[4];
    #pragma unroll
    for (int i = 0; i < 4; i++) {
        size_t off = (size_t)(nbase + i) * 64 + lane;
        zg[i] = frombf(r0g[off]) + frombf(r1g[off]);
        zi[i] = frombf(r0i[off]) + frombf(r1i[off]);
        a1[i] = b1[lane];
    }
    #pragma unroll 4
    for (int k = 0; k < 64; k++) {
        float w = W1[k * 64 + lane];
        #pragma unroll
        for (int i = 0; i < 4; i++) a1[i] += __shfl(zg[i], k, 64) * w;
    }
    #pragma unroll 4
    for (int k = 0; k < 64; k++) {
        float w = W1[(64 + k) * 64 + lane];
        #pragma unroll
        for (int i = 0; i < 4; i++) a1[i] += __shfl(zi[i], k, 64) * w;
    }
    #pragma unroll
    for (int i = 0; i < 4; i++) { a1[i] = fmaxf(a1[i], 0.f); g[i] = b2[lane]; }
    #pragma unroll 4
    for (int k = 0; k < 64; k++) {
        float w = W2[k * 64 + lane];
        #pragma unroll
        for (int i = 0; i < 4; i++) g[i] += __shfl(a1[i], k, 64) * w;
    }
    #pragma unroll
    for (int i = 0; i < 4; i++) {
        float gg = 1.0f / (1.0f + __expf(-g[i]));
        float zv = zg[i] * zi[i];
        out[(size_t)(nbase + i) * 64 + lane] = gg * zv + (1.0f - gg) * gg;
    }
}

// ================= aux finalize =================
__global__ void k_finalize(const float* __restrict__ stats, float* __restrict__ outAux) {
    int t = threadIdx.x;
    float s = (t < 16) ? stats[t] : 0.f;
    float aux = 0.f;
    for (int q = 0; q < 2; q++) {
        float a = 0.f;
        for (int e = 0; e < 4; e++) {
            float pr = __shfl(s, q * 8 + e, 64);
            float f  = __shfl(s, q * 8 + 4 + e, 64);
            a += (f / (float)NN) * (pr / (float)NN);
        }
        aux += 4.0f * a;
    }
    if (t == 0) *outAux = aux;
}

extern "C" void kernel_launch(void* const* d_in, const int* in_sizes, int n_in,
                              void* d_out, int out_size, void* d_ws, size_t ws_size,
                              hipStream_t stream) {
    (void)in_sizes; (void)n_in; (void)out_size; (void)ws_size;
    const float* features  = (const float*)d_in[0];
    const int*   node_types= (const int*)d_in[1];
    const int*   src       = (const int*)d_in[2];
    const int*   dst       = (const int*)d_in[3];
    const float* W_person  = (const float*)d_in[4];
    const float* b_person  = (const float*)d_in[5];
    const float* W_disease = (const float*)d_in[6];
    const float* b_disease = (const float*)d_in[7];
    const float* gat_W     = (const float*)d_in[8];
    const float* gat_al    = (const float*)d_in[9];
    const float* gat_ar    = (const float*)d_in[10];
    const float* gin_eps   = (const float*)d_in[11];
    const float* gin_W1    = (const float*)d_in[12];
    const float* gin_b1    = (const float*)d_in[13];
    const float* gin_W2    = (const float*)d_in[14];
    const float* gin_b2    = (const float*)d_in[15];
    const float* gat_gW    = (const float*)d_in[16];
    const float* gat_gb    = (const float*)d_in[17];
    const float* gat_eW1   = (const float*)d_in[18];
    const float* gat_eb1   = (const float*)d_in[19];
    const float* gat_eW2   = (const float*)d_in[20];
    const float* gat_eb2   = (const float*)d_in[21];
    const float* gin_gW    = (const float*)d_in[22];
    const float* gin_gb    = (const float*)d_in[23];
    const float* gin_eW1   = (const float*)d_in[24];
    const float* gin_eb1   = (const float*)d_in[25];
    const float* gin_eW2   = (const float*)d_in[26];
    const float* gin_eb2   = (const float*)d_in[27];
    const float* fg_W1     = (const float*)d_in[28];
    const float* fg_b1     = (const float*)d_in[29];
    const float* fg_W2     = (const float*)d_in[30];
    const float* fg_b2     = (const float*)d_in[31];
    float* out = (float*)d_out;

    float* ws = (float*)d_ws;
    size_t o = 0;
    float*    A  = ws + o; o += (size_t)NN * 64;   // h0 -> z_gin(final)
    float*    B  = ws + o; o += (size_t)NN * 64;   // GAT chain -> z_gat(final)
    float*    D  = ws + o; o += (size_t)NN * 64;   // gin l0 out; later r0g/r1g (bf16)
    float*    X  = ws + o; o += (size_t)NN * 64;   // GIN pre-MLP vector per layer
    unsigned* P0 = (unsigned*)(ws + o); o += (size_t)NN * 64;  // packed l0; later r0i/r1i
    unsigned* P1 = (unsigned*)(ws + o); o += (size_t)NN * 64;  // packed l1
    float* el0 = ws + o; o += (size_t)NN * 4;
    float* er0 = ws + o; o += (size_t)NN * 4;
    float* el1 = ws + o; o += (size_t)NN * 4;
    float* er1 = ws + o; o += (size_t)NN * 4;
    int*   cnt   = (int*)(ws + o); o += 8;
    float* stats = ws + o; o += 16;
    int* degcnt    = (int*)(ws + o); o += NN;
    int* row_start = (int*)(ws + o); o += NN + 4;
    int* cursor    = (int*)(ws + o); o += NN;
    int* bsums     = (int*)(ws + o); o += 256;
    int* bpre      = (int*)(ws + o); o += 256;
    int* csr_src   = (int*)(ws + o); o += EE;
    unsigned* aidx = (unsigned*)(ws + o); o += (size_t)8 * NN;
    float*    awt  = ws + o; o += (size_t)8 * NN;

    unsigned short* r0g = (unsigned short*)D;
    unsigned short* r1g = (unsigned short*)D + (size_t)NN * 64;
    unsigned short* r0i = (unsigned short*)P0;
    unsigned short* r1i = (unsigned short*)P0 + (size_t)NN * 64;

    const int NB_edge = EE / 256;   // 3125
    const int NB_node = NN / 4;     // 12500 (1 node/wave kernels)

    hipMemsetAsync(degcnt, 0, sizeof(int) * NN, stream);
    hipMemsetAsync(cnt, 0, sizeof(int) * 8 + sizeof(float) * 16, stream);

    // CSR build
    k_deg<<<NB_edge, 256, 0, stream>>>(dst, degcnt);
    k_scan_a<<<NBLK_SCAN, 256, 0, stream>>>(degcnt, bsums);
    k_scan_b<<<1, 256, 0, stream>>>(bsums, bpre);
    k_scan_c<<<NBLK_SCAN, 256, 0, stream>>>(degcnt, bpre, row_start, cursor);
    k_fill<<<NB_edge, 256, 0, stream>>>(src, dst, cursor, csr_src);

    // projection + GAT-l0 pre
    k_pre<<<NB16, 256, 0, stream>>>(features, node_types, W_person, b_person,
                                    W_disease, b_disease, gat_W, gat_al, gat_ar,
                                    A, P0, el0, er0);

    // layer 0
    k_edges<1><<<NB_node, 256, 0, stream>>>(row_start, csr_src, P0, el0, er0, A, A,
                                            gin_eps, B, X);
    k_dense<0><<<NB16, 256, 0, stream>>>(X, B, gin_W1, gin_b1, gin_W2, gin_b2, D,
                                         gat_W + 4096, gat_al + 64, gat_ar + 64, P1, el1, er1,
                                         nullptr, nullptr, nullptr, nullptr,
                                         nullptr, nullptr, nullptr, nullptr);
    // layer 1
    k_edges<0><<<NB_node, 256, 0, stream>>>(row_start, csr_src, P1, el1, er1, B, D,
                                            gin_eps + 1, B, X);
    k_dense<1><<<NB16, 256, 0, stream>>>(X, B, gin_W1 + 4096, gin_b1 + 64,
                                         gin_W2 + 4096, gin_b2 + 64, A,
                                         nullptr, nullptr, nullptr, nullptr, nullptr, nullptr,
                                         gat_gW, gat_gb, gin_gW, gin_gb,
                                         aidx, awt, cnt, stats);

    // expert-grouped MoE MLPs
    k_expert<<<25000, 256, 0, stream>>>(aidx, awt, cnt, B, A,
                                        gat_eW1, gat_eb1, gat_eW2, gat_eb2,
                                        gin_eW1, gin_eb1, gin_eW2, gin_eb2,
                                        r0g, r1g, r0i, r1i);

    // fusion + aux
    k_fusion<<<NB16, 256, 0, stream>>>(r0g, r1g, r0i, r1i, fg_W1, fg_b1, fg_W2, fg_b2, out);
    k_finalize<<<1, 64, 0, stream>>>(stats, out + (size_t)NN * 64);
}

// Round 6
// 466.816 us; speedup vs baseline: 6.7345x; 2.0125x over previous
//
#include <hip/hip_runtime.h>

#define NN 50000
#define EE 800000
#define NEG 0.2f
#define NBLK_SCAN 196   // ceil(NN/256)

typedef __attribute__((ext_vector_type(8))) short s8;
typedef __attribute__((ext_vector_type(4))) float f4;

__device__ __forceinline__ float leaky(float x) { return x > 0.f ? x : NEG * x; }
__device__ __forceinline__ unsigned bf16r(float x) {
    unsigned u = __float_as_uint(x);
    return (u + 0x7fffu + ((u >> 16) & 1u)) >> 16;
}
__device__ __forceinline__ float lo16(unsigned p) { return __uint_as_float(p << 16); }
__device__ __forceinline__ float hi16(unsigned p) { return __uint_as_float(p & 0xffff0000u); }

__device__ __forceinline__ s8 a_from_f32(const float* p) {
    float4 u = *reinterpret_cast<const float4*>(p);
    float4 v = *reinterpret_cast<const float4*>(p + 4);
    s8 r;
    r[0] = (short)bf16r(u.x); r[1] = (short)bf16r(u.y);
    r[2] = (short)bf16r(u.z); r[3] = (short)bf16r(u.w);
    r[4] = (short)bf16r(v.x); r[5] = (short)bf16r(v.y);
    r[6] = (short)bf16r(v.z); r[7] = (short)bf16r(v.w);
    return r;
}

// ================= CSR build =================
__global__ void k_deg(const int* __restrict__ dst, int* __restrict__ degcnt) {
    int e = blockIdx.x * 256 + threadIdx.x;
    atomicAdd(&degcnt[dst[e]], 1);
}

__global__ void k_scan_a(const int* __restrict__ degcnt, int* __restrict__ bsums) {
    __shared__ int sm[4];
    int i = blockIdx.x * 256 + threadIdx.x;
    int v = (i < NN) ? degcnt[i] : 0;
    #pragma unroll
    for (int o = 1; o < 64; o <<= 1) v += __shfl_xor(v, o, 64);
    if ((threadIdx.x & 63) == 0) sm[threadIdx.x >> 6] = v;
    __syncthreads();
    if (threadIdx.x == 0) bsums[blockIdx.x] = sm[0] + sm[1] + sm[2] + sm[3];
}

__global__ void k_scan_b(const int* __restrict__ bsums, int* __restrict__ bpre) {
    __shared__ int sm[256];
    int t = threadIdx.x;
    sm[t] = (t < NBLK_SCAN) ? bsums[t] : 0;
    __syncthreads();
    for (int off = 1; off < 256; off <<= 1) {
        int u = (t >= off) ? sm[t - off] : 0;
        __syncthreads();
        sm[t] += u;
        __syncthreads();
    }
    if (t < NBLK_SCAN) bpre[t] = (t == 0) ? 0 : sm[t - 1];
}

__global__ void k_scan_c(const int* __restrict__ degcnt, const int* __restrict__ bpre,
                         int* __restrict__ row_start, int* __restrict__ cursor) {
    __shared__ int sm[256];
    int t = threadIdx.x;
    int i = blockIdx.x * 256 + t;
    int v = (i < NN) ? degcnt[i] : 0;
    sm[t] = v;
    __syncthreads();
    for (int off = 1; off < 256; off <<= 1) {
        int u = (t >= off) ? sm[t - off] : 0;
        __syncthreads();
        sm[t] += u;
        __syncthreads();
    }
    int incl = sm[t];
    if (i < NN) { int rs = bpre[blockIdx.x] + incl - v; row_start[i] = rs; cursor[i] = rs; }
    if (i == NN - 1) row_start[NN] = bpre[blockIdx.x] + incl;
}

__global__ void k_fill(const int* __restrict__ src, const int* __restrict__ dst,
                       int* __restrict__ cursor, int* __restrict__ csr_src) {
    int e = blockIdx.x * 256 + threadIdx.x;
    int d = dst[e];
    int pos = atomicAdd(&cursor[d], 1);
    csr_src[pos] = src[e];
}

// ================= k_pre: MFMA projection (hp K=128, hd K=64, select) =================
__global__ __launch_bounds__(256) void k_pre(const float* __restrict__ feat,
        const int* __restrict__ types,
        const float* __restrict__ Wp, const float* __restrict__ bp,
        const float* __restrict__ Wd, const float* __restrict__ bd,
        float* __restrict__ h0f, unsigned short* __restrict__ h0b) {
    __shared__ unsigned short WpT[64 * 136];
    __shared__ unsigned short WdT[64 * 72];
    for (int idx = threadIdx.x; idx < 128 * 64; idx += 256) {
        int k = idx >> 6, n = idx & 63;
        WpT[n * 136 + k] = (unsigned short)bf16r(Wp[idx]);
    }
    for (int idx = threadIdx.x; idx < 64 * 64; idx += 256) {
        int k = idx >> 6, n = idx & 63;
        WdT[n * 72 + k] = (unsigned short)bf16r(Wd[idx]);
    }
    __syncthreads();
    int wv = threadIdx.x >> 6, lane = threadIdx.x & 63;
    int quad = lane >> 4, l16 = lane & 15;
    int gw = blockIdx.x * 4 + wv;
    int mtEnd = gw * 2 + 2; if (mtEnd > 3125) mtEnd = 3125;
    for (int mt = gw * 2; mt < mtEnd; mt++) {
        int row0 = mt * 16;
        const float* arow = feat + (size_t)(row0 + l16) * 128;
        f4 accp[4], accd[4];
        #pragma unroll
        for (int t = 0; t < 4; t++) { accp[t] = f4{0.f,0.f,0.f,0.f}; accd[t] = f4{0.f,0.f,0.f,0.f}; }
        #pragma unroll
        for (int ks = 0; ks < 4; ks++) {
            s8 a = a_from_f32(arow + ks * 32 + quad * 8);
            #pragma unroll
            for (int t = 0; t < 4; t++) {
                s8 b = *(const s8*)&WpT[(t * 16 + l16) * 136 + ks * 32 + quad * 8];
                accp[t] = __builtin_amdgcn_mfma_f32_16x16x32_bf16(a, b, accp[t], 0, 0, 0);
                if (ks < 2) {
                    s8 bd_ = *(const s8*)&WdT[(t * 16 + l16) * 72 + ks * 32 + quad * 8];
                    accd[t] = __builtin_amdgcn_mfma_f32_16x16x32_bf16(a, bd_, accd[t], 0, 0, 0);
                }
            }
        }
        int ty[4];
        #pragma unroll
        for (int r = 0; r < 4; r++) ty[r] = types[row0 + quad * 4 + r];
        #pragma unroll
        for (int t = 0; t < 4; t++) {
            int col = t * 16 + l16;
            float bpv = bp[col], bdv = bd[col];
            #pragma unroll
            for (int r = 0; r < 4; r++) {
                size_t off = (size_t)(row0 + quad * 4 + r) * 64 + col;
                float v = ty[r] ? (accd[t][r] + bdv) : (accp[t][r] + bpv);
                h0f[off] = v;
                h0b[off] = (unsigned short)bf16r(v);
            }
        }
    }
}

// ================= k_gatpre: hW = A@W (MFMA), el/er, pack P =================
__global__ __launch_bounds__(256) void k_gatpre(const unsigned short* __restrict__ Ab,
        const unsigned short* __restrict__ ginb, const float* __restrict__ W,
        const float* __restrict__ al, const float* __restrict__ ar,
        unsigned* __restrict__ P, float* __restrict__ el, float* __restrict__ er) {
    __shared__ unsigned short WT[64 * 72];
    for (int idx = threadIdx.x; idx < 64 * 64; idx += 256) {
        int k = idx >> 6, n = idx & 63;
        WT[n * 72 + k] = (unsigned short)bf16r(W[idx]);
    }
    __syncthreads();
    int wv = threadIdx.x >> 6, lane = threadIdx.x & 63;
    int quad = lane >> 4, l16 = lane & 15;
    int gw = blockIdx.x * 4 + wv;
    int mtEnd = gw * 2 + 2; if (mtEnd > 3125) mtEnd = 3125;
    for (int mt = gw * 2; mt < mtEnd; mt++) {
        int row0 = mt * 16;
        const unsigned short* arow = Ab + (size_t)(row0 + l16) * 64;
        s8 a0 = *(const s8*)(arow + quad * 8);
        s8 a1 = *(const s8*)(arow + 32 + quad * 8);
        f4 acc[4];
        #pragma unroll
        for (int t = 0; t < 4; t++) {
            acc[t] = f4{0.f,0.f,0.f,0.f};
            s8 b0 = *(const s8*)&WT[(t * 16 + l16) * 72 + quad * 8];
            acc[t] = __builtin_amdgcn_mfma_f32_16x16x32_bf16(a0, b0, acc[t], 0, 0, 0);
            s8 b1_ = *(const s8*)&WT[(t * 16 + l16) * 72 + 32 + quad * 8];
            acc[t] = __builtin_amdgcn_mfma_f32_16x16x32_bf16(a1, b1_, acc[t], 0, 0, 0);
        }
        #pragma unroll
        for (int t = 0; t < 4; t++) {
            int col = t * 16 + l16;
            float alv = al[col], arv = ar[col];
            #pragma unroll
            for (int r = 0; r < 4; r++) {
                int row = row0 + quad * 4 + r;
                float hw = acc[t][r];
                unsigned short g16 = ginb[(size_t)row * 64 + col];
                P[(size_t)row * 64 + col] = bf16r(hw) | ((unsigned)g16 << 16);
                float pl = hw * alv, pr = hw * arv;
                #pragma unroll
                for (int m = 1; m < 16; m <<= 1) {
                    pl += __shfl_xor(pl, m, 64);
                    pr += __shfl_xor(pr, m, 64);
                }
                if (l16 == 0) {
                    el[(size_t)row * 4 + t] = pl;
                    er[(size_t)row * 4 + t] = pr;
                }
            }
        }
    }
}

// ================= edge walk: 1 node/wave (round-5 structure), bf16 outputs ========
template <int RELU>
__global__ void k_edges(const int* __restrict__ rows, const int* __restrict__ csr,
                        const unsigned* __restrict__ Pin,
                        const float* __restrict__ el, const float* __restrict__ er,
                        const float* __restrict__ gat_in, const float* __restrict__ gin_in,
                        const float* __restrict__ eps_p,
                        float* __restrict__ vgf, unsigned short* __restrict__ vgb,
                        unsigned short* __restrict__ xb) {
    __shared__ float ews[4][256];
    int wv = threadIdx.x >> 6, lane = threadIdx.x & 63;
    int n = blockIdx.x * 4 + wv;
    int st = rows[n], dg = rows[n + 1] - st;
    int hd = lane >> 4;
    float4 erv = *reinterpret_cast<const float4*>(er + (size_t)n * 4);
    float accg = 0.f, acci = 0.f, ssum = 0.f;
    for (int base = 0; base < dg; base += 64) {
        int rem = dg - base; if (rem > 64) rem = 64;
        int myi = 0;
        if (lane < rem) {
            myi = csr[st + base + lane];
            float4 lv = *reinterpret_cast<const float4*>(el + (size_t)myi * 4);
            float4 ev;
            ev.x = __expf(leaky(lv.x + erv.x));
            ev.y = __expf(leaky(lv.y + erv.y));
            ev.z = __expf(leaky(lv.z + erv.z));
            ev.w = __expf(leaky(lv.w + erv.w));
            *reinterpret_cast<float4*>(&ews[wv][lane * 4]) = ev;
        }
        int j = 0;
        for (; j + 4 <= rem; j += 4) {
            int s0 = __shfl(myi, j, 64),     s1 = __shfl(myi, j + 1, 64);
            int s2 = __shfl(myi, j + 2, 64), s3 = __shfl(myi, j + 3, 64);
            unsigned p0 = Pin[(size_t)s0 * 64 + lane];
            unsigned p1 = Pin[(size_t)s1 * 64 + lane];
            unsigned p2 = Pin[(size_t)s2 * 64 + lane];
            unsigned p3 = Pin[(size_t)s3 * 64 + lane];
            float a0 = ews[wv][(j + 0) * 4 + hd];
            float a1 = ews[wv][(j + 1) * 4 + hd];
            float a2 = ews[wv][(j + 2) * 4 + hd];
            float a3 = ews[wv][(j + 3) * 4 + hd];
            accg += a0 * lo16(p0) + a1 * lo16(p1) + a2 * lo16(p2) + a3 * lo16(p3);
            acci += hi16(p0) + hi16(p1) + hi16(p2) + hi16(p3);
            ssum += a0 + a1 + a2 + a3;
        }
        for (; j < rem; j++) {
            int s0 = __shfl(myi, j, 64);
            unsigned p0 = Pin[(size_t)s0 * 64 + lane];
            float a0 = ews[wv][j * 4 + hd];
            accg += a0 * lo16(p0); acci += hi16(p0); ssum += a0;
        }
    }
    float vg = accg / (ssum + 1e-9f) + gat_in[(size_t)n * 64 + lane];
    if (RELU) vg = fmaxf(vg, 0.f);
    float invd = 1.0f / fmaxf((float)dg, 1.0f);
    float x = (1.0f + eps_p[0]) * gin_in[(size_t)n * 64 + lane] + acci * invd;
    size_t off = (size_t)n * 64 + lane;
    vgf[off] = vg;
    vgb[off] = (unsigned short)bf16r(vg);
    xb[off] = (unsigned short)bf16r(x);
}

// ================= generic MFMA GEMM N=K=64: out = act(A@W + b) =================
template <int RELU, int WF32>
__global__ __launch_bounds__(256) void k_gemm64(const unsigned short* __restrict__ Ab,
        const float* __restrict__ W, const float* __restrict__ bias,
        unsigned short* __restrict__ outb, float* __restrict__ outf) {
    __shared__ unsigned short WT[64 * 72];
    for (int idx = threadIdx.x; idx < 64 * 64; idx += 256) {
        int k = idx >> 6, n = idx & 63;
        WT[n * 72 + k] = (unsigned short)bf16r(W[idx]);
    }
    __syncthreads();
    int wv = threadIdx.x >> 6, lane = threadIdx.x & 63;
    int quad = lane >> 4, l16 = lane & 15;
    int gw = blockIdx.x * 4 + wv;
    int mtEnd = gw * 2 + 2; if (mtEnd > 3125) mtEnd = 3125;
    for (int mt = gw * 2; mt < mtEnd; mt++) {
        int row0 = mt * 16;
        const unsigned short* arow = Ab + (size_t)(row0 + l16) * 64;
        s8 a0 = *(const s8*)(arow + quad * 8);
        s8 a1 = *(const s8*)(arow + 32 + quad * 8);
        f4 acc[4];
        #pragma unroll
        for (int t = 0; t < 4; t++) {
            acc[t] = f4{0.f,0.f,0.f,0.f};
            s8 b0 = *(const s8*)&WT[(t * 16 + l16) * 72 + quad * 8];
            acc[t] = __builtin_amdgcn_mfma_f32_16x16x32_bf16(a0, b0, acc[t], 0, 0, 0);
            s8 b1_ = *(const s8*)&WT[(t * 16 + l16) * 72 + 32 + quad * 8];
            acc[t] = __builtin_amdgcn_mfma_f32_16x16x32_bf16(a1, b1_, acc[t], 0, 0, 0);
        }
        #pragma unroll
        for (int t = 0; t < 4; t++) {
            int col = t * 16 + l16;
            float bv = bias[col];
            #pragma unroll
            for (int r = 0; r < 4; r++) {
                size_t off = (size_t)(row0 + quad * 4 + r) * 64 + col;
                float v = acc[t][r] + bv;
                if (RELU) v = fmaxf(v, 0.f);
                outb[off] = (unsigned short)bf16r(v);
                if (WF32) outf[off] = v;
            }
        }
    }
}

// ================= MoE routing: dense weights + stats =================
__global__ void k_route(const float* __restrict__ zg, const float* __restrict__ zi,
                        const float* __restrict__ ggW, const float* __restrict__ ggb,
                        const float* __restrict__ igW, const float* __restrict__ igb,
                        float* __restrict__ wgtg, float* __restrict__ wgti,
                        float* __restrict__ stats) {
    __shared__ float sstat[16];
    if (threadIdx.x < 16) sstat[threadIdx.x] = 0.f;
    __syncthreads();
    int wv = threadIdx.x >> 6, lane = threadIdx.x & 63;
    int nbase = (blockIdx.x * 4 + wv) * 4;
    float4 gw_g = *reinterpret_cast<const float4*>(ggW + lane * 4);
    float4 gw_i = *reinterpret_cast<const float4*>(igW + lane * 4);
    float sp[2][4] = {{0,0,0,0},{0,0,0,0}};
    float sh[2][4] = {{0,0,0,0},{0,0,0,0}};
    for (int q = 0; q < 2; q++) {
        const float* Z = q ? zi : zg;
        float4 gw = q ? gw_i : gw_g;
        const float* gb = q ? igb : ggb;
        float g0 = gb[0], g1 = gb[1], g2 = gb[2], g3 = gb[3];
        #pragma unroll
        for (int i = 0; i < 4; i++) {
            float v = Z[(size_t)(nbase + i) * 64 + lane];
            float p0 = v * gw.x, p1 = v * gw.y, p2 = v * gw.z, p3 = v * gw.w;
            #pragma unroll
            for (int m = 1; m < 64; m <<= 1) {
                p0 += __shfl_xor(p0, m, 64); p1 += __shfl_xor(p1, m, 64);
                p2 += __shfl_xor(p2, m, 64); p3 += __shfl_xor(p3, m, 64);
            }
            p0 += g0; p1 += g1; p2 += g2; p3 += g3;
            float mx = fmaxf(fmaxf(p0, p1), fmaxf(p2, p3));
            float e0 = __expf(p0 - mx), e1 = __expf(p1 - mx);
            float e2 = __expf(p2 - mx), e3 = __expf(p3 - mx);
            float inv = 1.0f / (e0 + e1 + e2 + e3);
            float pr[4] = {e0 * inv, e1 * inv, e2 * inv, e3 * inv};
            int i1 = 0; float v1 = pr[0];
            #pragma unroll
            for (int e = 1; e < 4; e++) if (pr[e] > v1) { v1 = pr[e]; i1 = e; }
            int i2 = -1; float v2 = -1.f;
            #pragma unroll
            for (int e = 0; e < 4; e++) if (e != i1 && pr[e] > v2) { v2 = pr[e]; i2 = e; }
            float wsum = v1 + v2;
            float w0 = v1 / wsum, w1 = v2 / wsum;
            #pragma unroll
            for (int e = 0; e < 4; e++) sp[q][e] += pr[e];
            sh[q][i1] += 1.f; sh[q][i2] += 1.f;
            if (lane == 0) {
                float wq[4] = {0.f, 0.f, 0.f, 0.f};
                wq[i1] = w0; wq[i2] = w1;
                float* WD = q ? wgti : wgtg;
                size_t b = (size_t)(nbase + i) * 4;
                WD[b + 0] = wq[0]; WD[b + 1] = wq[1]; WD[b + 2] = wq[2]; WD[b + 3] = wq[3];
            }
        }
    }
    if (lane == 0) {
        #pragma unroll
        for (int q = 0; q < 2; q++)
            #pragma unroll
            for (int e = 0; e < 4; e++) {
                atomicAdd(&sstat[q * 8 + e], sp[q][e]);
                atomicAdd(&sstat[q * 8 + 4 + e], sh[q][e]);
            }
    }
    __syncthreads();
    if (threadIdx.x >= 32 && threadIdx.x < 48) {
        int t = threadIdx.x - 32;
        atomicAdd(&stats[t], sstat[t]);
    }
}

// ================= dense-all experts (MFMA), weighted accumulate =================
__global__ __launch_bounds__(256) void k_expert(const unsigned short* __restrict__ Ab,
        const float* __restrict__ eW1, const float* __restrict__ eb1,
        const float* __restrict__ eW2, const float* __restrict__ eb2,
        const float* __restrict__ wgt, float* __restrict__ moef,
        unsigned short* __restrict__ ub, int qoff) {
    __shared__ unsigned short w1t[4 * 32 * 72];
    __shared__ unsigned short w2t[4 * 64 * 40];
    __shared__ unsigned short y1s[4][16 * 40];
    for (int g = threadIdx.x; g < 8192; g += 256) {
        int e = g >> 11, rem = g & 2047;
        int k = rem >> 5, n = rem & 31;
        w1t[e * 2304 + n * 72 + k] = (unsigned short)bf16r(eW1[g]);
    }
    for (int g = threadIdx.x; g < 8192; g += 256) {
        int e = g >> 11, rem = g & 2047;
        int k = rem >> 6, n = rem & 63;
        w2t[e * 2560 + n * 40 + k] = (unsigned short)bf16r(eW2[g]);
    }
    __syncthreads();
    int wv = threadIdx.x >> 6, lane = threadIdx.x & 63;
    int quad = lane >> 4, l16 = lane & 15;
    int gw = blockIdx.x * 4 + wv;
    int mtEnd = gw * 4 + 4; if (mtEnd > 3125) mtEnd = 3125;
    for (int mt = gw * 4; mt < mtEnd; mt++) {
        int row0 = mt * 16;
        const unsigned short* arow = Ab + (size_t)(row0 + l16) * 64;
        s8 a0 = *(const s8*)(arow + quad * 8);
        s8 a1 = *(const s8*)(arow + 32 + quad * 8);
        f4 outacc[4];
        #pragma unroll
        for (int t = 0; t < 4; t++) outacc[t] = f4{0.f,0.f,0.f,0.f};
        for (int e = 0; e < 4; e++) {
            f4 acc1[2];
            #pragma unroll
            for (int t = 0; t < 2; t++) {
                acc1[t] = f4{0.f,0.f,0.f,0.f};
                s8 b0 = *(const s8*)&w1t[e * 2304 + (t * 16 + l16) * 72 + quad * 8];
                acc1[t] = __builtin_amdgcn_mfma_f32_16x16x32_bf16(a0, b0, acc1[t], 0, 0, 0);
                s8 b1_ = *(const s8*)&w1t[e * 2304 + (t * 16 + l16) * 72 + 32 + quad * 8];
                acc1[t] = __builtin_amdgcn_mfma_f32_16x16x32_bf16(a1, b1_, acc1[t], 0, 0, 0);
            }
            #pragma unroll
            for (int t = 0; t < 2; t++) {
                float b1v = eb1[e * 32 + t * 16 + l16];
                #pragma unroll
                for (int r = 0; r < 4; r++) {
                    float v = fmaxf(acc1[t][r] + b1v, 0.f);
                    y1s[wv][(quad * 4 + r) * 40 + t * 16 + l16] = (unsigned short)bf16r(v);
                }
            }
            s8 a2 = *(const s8*)&y1s[wv][l16 * 40 + quad * 8];
            f4 acc2[4];
            #pragma unroll
            for (int t = 0; t < 4; t++) {
                acc2[t] = f4{0.f,0.f,0.f,0.f};
                s8 b2_ = *(const s8*)&w2t[e * 2560 + (t * 16 + l16) * 40 + quad * 8];
                acc2[t] = __builtin_amdgcn_mfma_f32_16x16x32_bf16(a2, b2_, acc2[t], 0, 0, 0);
            }
            #pragma unroll
            for (int t = 0; t < 4; t++) {
                float b2v = eb2[e * 64 + t * 16 + l16];
                #pragma unroll
                for (int r = 0; r < 4; r++) {
                    float we = wgt[(size_t)(row0 + quad * 4 + r) * 4 + e];
                    outacc[t][r] += we * (acc2[t][r] + b2v);
                }
            }
        }
        #pragma unroll
        for (int t = 0; t < 4; t++) {
            int col = t * 16 + l16;
            #pragma unroll
            for (int r = 0; r < 4; r++) {
                int row = row0 + quad * 4 + r;
                float v = outacc[t][r];
                moef[(size_t)row * 64 + col] = v;
                ub[(size_t)row * 128 + qoff + col] = (unsigned short)bf16r(v);
            }
        }
    }
}

// ================= fusion gate (MFMA, K=128 then K=64) =================
__global__ __launch_bounds__(256) void k_fusion(const unsigned short* __restrict__ ubuf,
        const float* __restrict__ W1, const float* __restrict__ b1,
        const float* __restrict__ W2, const float* __restrict__ b2,
        const float* __restrict__ moegf, const float* __restrict__ moeif,
        float* __restrict__ out) {
    __shared__ unsigned short W1T[64 * 136];
    __shared__ unsigned short W2T[64 * 72];
    __shared__ unsigned short y1s[4][16 * 72];
    for (int idx = threadIdx.x; idx < 128 * 64; idx += 256) {
        int k = idx >> 6, n = idx & 63;
        W1T[n * 136 + k] = (unsigned short)bf16r(W1[idx]);
    }
    for (int idx = threadIdx.x; idx < 64 * 64; idx += 256) {
        int k = idx >> 6, n = idx & 63;
        W2T[n * 72 + k] = (unsigned short)bf16r(W2[idx]);
    }
    __syncthreads();
    int wv = threadIdx.x >> 6, lane = threadIdx.x & 63;
    int quad = lane >> 4, l16 = lane & 15;
    int gw = blockIdx.x * 4 + wv;
    int mtEnd = gw * 2 + 2; if (mtEnd > 3125) mtEnd = 3125;
    for (int mt = gw * 2; mt < mtEnd; mt++) {
        int row0 = mt * 16;
        const unsigned short* arow = ubuf + (size_t)(row0 + l16) * 128;
        f4 acc1[4];
        #pragma unroll
        for (int t = 0; t < 4; t++) acc1[t] = f4{0.f,0.f,0.f,0.f};
        #pragma unroll
        for (int ks = 0; ks < 4; ks++) {
            s8 a = *(const s8*)(arow + ks * 32 + quad * 8);
            #pragma unroll
            for (int t = 0; t < 4; t++) {
                s8 b = *(const s8*)&W1T[(t * 16 + l16) * 136 + ks * 32 + quad * 8];
                acc1[t] = __builtin_amdgcn_mfma_f32_16x16x32_bf16(a, b, acc1[t], 0, 0, 0);
            }
        }
        #pragma unroll
        for (int t = 0; t < 4; t++) {
            float b1v = b1[t * 16 + l16];
            #pragma unroll
            for (int r = 0; r < 4; r++) {
                float v = fmaxf(acc1[t][r] + b1v, 0.f);
                y1s[wv][(quad * 4 + r) * 72 + t * 16 + l16] = (unsigned short)bf16r(v);
            }
        }
        f4 acc2[4];
        #pragma unroll
        for (int t = 0; t < 4; t++) acc2[t] = f4{0.f,0.f,0.f,0.f};
        #pragma unroll
        for (int ks = 0; ks < 2; ks++) {
            s8 a = *(const s8*)&y1s[wv][l16 * 72 + ks * 32 + quad * 8];
            #pragma unroll
            for (int t = 0; t < 4; t++) {
                s8 b = *(const s8*)&W2T[(t * 16 + l16) * 72 + ks * 32 + quad * 8];
                acc2[t] = __builtin_amdgcn_mfma_f32_16x16x32_bf16(a, b, acc2[t], 0, 0, 0);
            }
        }
        #pragma unroll
        for (int t = 0; t < 4; t++) {
            int col = t * 16 + l16;
            float b2v = b2[col];
            #pragma unroll
            for (int r = 0; r < 4; r++) {
                int row = row0 + quad * 4 + r;
                float g = 1.0f / (1.0f + __expf(-(acc2[t][r] + b2v)));
                float zgv = moegf[(size_t)row * 64 + col];
                float ziv = moeif[(size_t)row * 64 + col];
                out[(size_t)row * 64 + col] = g * zgv * ziv + (1.0f - g) * g;
            }
        }
    }
}

// ================= aux finalize =================
__global__ void k_finalize(const float* __restrict__ stats, float* __restrict__ outAux) {
    int t = threadIdx.x;
    float s = (t < 16) ? stats[t] : 0.f;
    float aux = 0.f;
    for (int q = 0; q < 2; q++) {
        float a = 0.f;
        for (int e = 0; e < 4; e++) {
            float pr = __shfl(s, q * 8 + e, 64);
            float f  = __shfl(s, q * 8 + 4 + e, 64);
            a += (f / (float)NN) * (pr / (float)NN);
        }
        aux += 4.0f * a;
    }
    if (t == 0) *outAux = aux;
}

extern "C" void kernel_launch(void* const* d_in, const int* in_sizes, int n_in,
                              void* d_out, int out_size, void* d_ws, size_t ws_size,
                              hipStream_t stream) {
    (void)in_sizes; (void)n_in; (void)out_size; (void)ws_size;
    const float* features  = (const float*)d_in[0];
    const int*   node_types= (const int*)d_in[1];
    const int*   src       = (const int*)d_in[2];
    const int*   dst       = (const int*)d_in[3];
    const float* W_person  = (const float*)d_in[4];
    const float* b_person  = (const float*)d_in[5];
    const float* W_disease = (const float*)d_in[6];
    const float* b_disease = (const float*)d_in[7];
    const float* gat_W     = (const float*)d_in[8];
    const float* gat_al    = (const float*)d_in[9];
    const float* gat_ar    = (const float*)d_in[10];
    const float* gin_eps   = (const float*)d_in[11];
    const float* gin_W1    = (const float*)d_in[12];
    const float* gin_b1    = (const float*)d_in[13];
    const float* gin_W2    = (const float*)d_in[14];
    const float* gin_b2    = (const float*)d_in[15];
    const float* gat_gW    = (const float*)d_in[16];
    const float* gat_gb    = (const float*)d_in[17];
    const float* gat_eW1   = (const float*)d_in[18];
    const float* gat_eb1   = (const float*)d_in[19];
    const float* gat_eW2   = (const float*)d_in[20];
    const float* gat_eb2   = (const float*)d_in[21];
    const float* gin_gW    = (const float*)d_in[22];
    const float* gin_gb    = (const float*)d_in[23];
    const float* gin_eW1   = (const float*)d_in[24];
    const float* gin_eb1   = (const float*)d_in[25];
    const float* gin_eW2   = (const float*)d_in[26];
    const float* gin_eb2   = (const float*)d_in[27];
    const float* fg_W1     = (const float*)d_in[28];
    const float* fg_b1     = (const float*)d_in[29];
    const float* fg_W2     = (const float*)d_in[30];
    const float* fg_b2     = (const float*)d_in[31];
    float* out = (float*)d_out;

    float* ws = (float*)d_ws;
    size_t o = 0;
    float* A = ws + o; o += (size_t)NN * 64;        // h0f; later ub (bf16 N x 128)
    float* B = ws + o; o += (size_t)NN * 64;        // vgf chain; later moegf
    float* C = ws + o; o += (size_t)NN * 64;        // ginf chain; later moeif
    unsigned short* Dh = (unsigned short*)(ws + o); o += (size_t)NN * 32;  // h0b; later y1b
    unsigned short* E  = (unsigned short*)(ws + o); o += (size_t)NN * 32;  // vgb
    unsigned short* F  = (unsigned short*)(ws + o); o += (size_t)NN * 32;  // ginb
    unsigned short* G  = (unsigned short*)(ws + o); o += (size_t)NN * 32;  // xb
    unsigned* P = (unsigned*)(ws + o); o += (size_t)NN * 64;  // packed hW|gin
    float* el = ws + o; o += (size_t)NN * 4;
    float* er = ws + o; o += (size_t)NN * 4;
    float* wgtg = ws + o; o += (size_t)NN * 4;
    float* wgti = ws + o; o += (size_t)NN * 4;
    float* stats = ws + o; o += 16;
    int* degcnt    = (int*)(ws + o); o += NN;
    int* row_start = (int*)(ws + o); o += NN + 4;
    int* cursor    = (int*)(ws + o); o += NN;
    int* bsums     = (int*)(ws + o); o += 256;
    int* bpre      = (int*)(ws + o); o += 256;
    int* csr_src   = (int*)(ws + o); o += EE;

    float* h0f = A;
    unsigned short* h0b = Dh;
    unsigned short* y1b = Dh;                 // reuse after gatpre(l0)
    unsigned short* ub = (unsigned short*)A;  // reuse after edges(l0)
    float* moegf = B;                         // reuse after k_route
    float* moeif = C;

    const int NB_edge = EE / 256;   // 3125
    const int NB_node = NN / 4;     // 12500
    const int NBG = 391;            // gemm-grid: 1564 waves x 2 mtiles
    const int NBE = 196;            // expert-grid: 784 waves x 4 mtiles

    hipMemsetAsync(degcnt, 0, sizeof(int) * NN, stream);
    hipMemsetAsync(stats, 0, sizeof(float) * 16, stream);

    // CSR build
    k_deg<<<NB_edge, 256, 0, stream>>>(dst, degcnt);
    k_scan_a<<<NBLK_SCAN, 256, 0, stream>>>(degcnt, bsums);
    k_scan_b<<<1, 256, 0, stream>>>(bsums, bpre);
    k_scan_c<<<NBLK_SCAN, 256, 0, stream>>>(degcnt, bpre, row_start, cursor);
    k_fill<<<NB_edge, 256, 0, stream>>>(src, dst, cursor, csr_src);

    // projection
    k_pre<<<NBG, 256, 0, stream>>>(features, node_types, W_person, b_person,
                                   W_disease, b_disease, h0f, h0b);

    // ---- layer 0 ----
    k_gatpre<<<NBG, 256, 0, stream>>>(h0b, h0b, gat_W, gat_al, gat_ar, P, el, er);
    k_edges<1><<<NB_node, 256, 0, stream>>>(row_start, csr_src, P, el, er, h0f, h0f,
                                            gin_eps, B, E, G);
    k_gemm64<1, 0><<<NBG, 256, 0, stream>>>(G, gin_W1, gin_b1, y1b, nullptr);
    k_gemm64<1, 1><<<NBG, 256, 0, stream>>>(y1b, gin_W2, gin_b2, F, C);

    // ---- layer 1 ----
    k_gatpre<<<NBG, 256, 0, stream>>>(E, F, gat_W + 4096, gat_al + 64, gat_ar + 64, P, el, er);
    k_edges<0><<<NB_node, 256, 0, stream>>>(row_start, csr_src, P, el, er, B, C,
                                            gin_eps + 1, B, E, G);
    k_gemm64<1, 0><<<NBG, 256, 0, stream>>>(G, gin_W1 + 4096, gin_b1 + 64, y1b, nullptr);
    k_gemm64<0, 1><<<NBG, 256, 0, stream>>>(y1b, gin_W2 + 4096, gin_b2 + 64, F, C);

    // ---- MoE ----
    k_route<<<NB_node / 4, 256, 0, stream>>>(B, C, gat_gW, gat_gb, gin_gW, gin_gb,
                                             wgtg, wgti, stats);
    k_expert<<<NBE, 256, 0, stream>>>(E, gat_eW1, gat_eb1, gat_eW2, gat_eb2,
                                      wgtg, moegf, ub, 0);
    k_expert<<<NBE, 256, 0, stream>>>(F, gin_eW1, gin_eb1, gin_eW2, gin_eb2,
                                      wgti, moeif, ub, 64);

    // ---- fusion + aux ----
    k_fusion<<<NBG, 256, 0, stream>>>(ub, fg_W1, fg_b1, fg_W2, fg_b2, moegf, moeif, out);
    k_finalize<<<1, 64, 0, stream>>>(stats, out + (size_t)NN * 64);
}

// Round 7
// 411.934 us; speedup vs baseline: 7.6317x; 1.1332x over previous
//
#include <hip/hip_runtime.h>

#define NN 50000
#define EE 800000
#define NEG 0.2f
#define NBLK_SCAN 196   // ceil(NN/256)
#define NBG 391         // gemm grid: 1564 waves x 2 mtiles >= 3125
#define NBE 196         // expert grid: 784 waves x 4 mtiles >= 3125
#define RBLK 782        // route grid: 64 nodes/block

typedef __attribute__((ext_vector_type(8))) short s8;
typedef __attribute__((ext_vector_type(4))) float f4;

__device__ __forceinline__ float leaky(float x) { return x > 0.f ? x : NEG * x; }
__device__ __forceinline__ unsigned bf16r(float x) {
    unsigned u = __float_as_uint(x);
    return (u + 0x7fffu + ((u >> 16) & 1u)) >> 16;
}
__device__ __forceinline__ float lo16(unsigned p) { return __uint_as_float(p << 16); }
__device__ __forceinline__ float hi16(unsigned p) { return __uint_as_float(p & 0xffff0000u); }

__device__ __forceinline__ s8 a_from_f32(const float* p) {
    float4 u = *reinterpret_cast<const float4*>(p);
    float4 v = *reinterpret_cast<const float4*>(p + 4);
    s8 r;
    r[0] = (short)bf16r(u.x); r[1] = (short)bf16r(u.y);
    r[2] = (short)bf16r(u.z); r[3] = (short)bf16r(u.w);
    r[4] = (short)bf16r(v.x); r[5] = (short)bf16r(v.y);
    r[6] = (short)bf16r(v.z); r[7] = (short)bf16r(v.w);
    return r;
}

// ================= CSR build =================
__global__ void k_deg(const int* __restrict__ dst, int* __restrict__ degcnt) {
    int e = blockIdx.x * 256 + threadIdx.x;
    atomicAdd(&degcnt[dst[e]], 1);
}

__global__ void k_scan_a(const int* __restrict__ degcnt, int* __restrict__ bsums) {
    __shared__ int sm[4];
    int i = blockIdx.x * 256 + threadIdx.x;
    int v = (i < NN) ? degcnt[i] : 0;
    #pragma unroll
    for (int o = 1; o < 64; o <<= 1) v += __shfl_xor(v, o, 64);
    if ((threadIdx.x & 63) == 0) sm[threadIdx.x >> 6] = v;
    __syncthreads();
    if (threadIdx.x == 0) bsums[blockIdx.x] = sm[0] + sm[1] + sm[2] + sm[3];
}

__global__ void k_scan_b(const int* __restrict__ bsums, int* __restrict__ bpre) {
    __shared__ int sm[256];
    int t = threadIdx.x;
    sm[t] = (t < NBLK_SCAN) ? bsums[t] : 0;
    __syncthreads();
    for (int off = 1; off < 256; off <<= 1) {
        int u = (t >= off) ? sm[t - off] : 0;
        __syncthreads();
        sm[t] += u;
        __syncthreads();
    }
    if (t < NBLK_SCAN) bpre[t] = (t == 0) ? 0 : sm[t - 1];
}

__global__ void k_scan_c(const int* __restrict__ degcnt, const int* __restrict__ bpre,
                         int* __restrict__ row_start, int* __restrict__ cursor) {
    __shared__ int sm[256];
    int t = threadIdx.x;
    int i = blockIdx.x * 256 + t;
    int v = (i < NN) ? degcnt[i] : 0;
    sm[t] = v;
    __syncthreads();
    for (int off = 1; off < 256; off <<= 1) {
        int u = (t >= off) ? sm[t - off] : 0;
        __syncthreads();
        sm[t] += u;
        __syncthreads();
    }
    int incl = sm[t];
    if (i < NN) { int rs = bpre[blockIdx.x] + incl - v; row_start[i] = rs; cursor[i] = rs; }
    if (i == NN - 1) row_start[NN] = bpre[blockIdx.x] + incl;
}

__global__ void k_fill(const int* __restrict__ src, const int* __restrict__ dst,
                       int* __restrict__ cursor, int* __restrict__ csr_src) {
    int e = blockIdx.x * 256 + threadIdx.x;
    int d = dst[e];
    int pos = atomicAdd(&cursor[d], 1);
    csr_src[pos] = src[e];
}

// ======= k_pre: MFMA projection + GAT-l0 pre (hW0, el0, er0, P0) fused =======
__global__ __launch_bounds__(256) void k_pre(const float* __restrict__ feat,
        const int* __restrict__ types,
        const float* __restrict__ Wp, const float* __restrict__ bp,
        const float* __restrict__ Wd, const float* __restrict__ bd,
        const float* __restrict__ gW, const float* __restrict__ al,
        const float* __restrict__ ar,
        float* __restrict__ h0f, unsigned* __restrict__ P,
        float* __restrict__ el, float* __restrict__ er) {
    __shared__ unsigned short WpT[64 * 136];
    __shared__ unsigned short WdT[64 * 72];
    __shared__ unsigned short WgT[64 * 72];
    __shared__ unsigned short y0s[4][16 * 72];
    for (int idx = threadIdx.x; idx < 128 * 64; idx += 256) {
        int k = idx >> 6, n = idx & 63;
        WpT[n * 136 + k] = (unsigned short)bf16r(Wp[idx]);
    }
    for (int idx = threadIdx.x; idx < 64 * 64; idx += 256) {
        int k = idx >> 6, n = idx & 63;
        WdT[n * 72 + k] = (unsigned short)bf16r(Wd[idx]);
        WgT[n * 72 + k] = (unsigned short)bf16r(gW[idx]);
    }
    __syncthreads();
    int wv = threadIdx.x >> 6, lane = threadIdx.x & 63;
    int quad = lane >> 4, l16 = lane & 15;
    int gw = blockIdx.x * 4 + wv;
    int mtEnd = gw * 2 + 2; if (mtEnd > 3125) mtEnd = 3125;
    for (int mt = gw * 2; mt < mtEnd; mt++) {
        int row0 = mt * 16;
        const float* arow = feat + (size_t)(row0 + l16) * 128;
        f4 accp[4], accd[4];
        #pragma unroll
        for (int t = 0; t < 4; t++) { accp[t] = f4{0.f,0.f,0.f,0.f}; accd[t] = f4{0.f,0.f,0.f,0.f}; }
        #pragma unroll
        for (int ks = 0; ks < 4; ks++) {
            s8 a = a_from_f32(arow + ks * 32 + quad * 8);
            #pragma unroll
            for (int t = 0; t < 4; t++) {
                s8 b = *(const s8*)&WpT[(t * 16 + l16) * 136 + ks * 32 + quad * 8];
                accp[t] = __builtin_amdgcn_mfma_f32_16x16x32_bf16(a, b, accp[t], 0, 0, 0);
                if (ks < 2) {
                    s8 bd_ = *(const s8*)&WdT[(t * 16 + l16) * 72 + ks * 32 + quad * 8];
                    accd[t] = __builtin_amdgcn_mfma_f32_16x16x32_bf16(a, bd_, accd[t], 0, 0, 0);
                }
            }
        }
        int ty[4];
        #pragma unroll
        for (int r = 0; r < 4; r++) ty[r] = types[row0 + quad * 4 + r];
        float vv[4][4];
        #pragma unroll
        for (int t = 0; t < 4; t++) {
            int col = t * 16 + l16;
            float bpv = bp[col], bdv = bd[col];
            #pragma unroll
            for (int r = 0; r < 4; r++) {
                float v = ty[r] ? (accd[t][r] + bdv) : (accp[t][r] + bpv);
                vv[t][r] = v;
                h0f[(size_t)(row0 + quad * 4 + r) * 64 + col] = v;
                y0s[wv][(quad * 4 + r) * 72 + col] = (unsigned short)bf16r(v);
            }
        }
        // GAT-l0 pre: hW = h0 @ gW
        s8 a0 = *(const s8*)&y0s[wv][l16 * 72 + quad * 8];
        s8 a1 = *(const s8*)&y0s[wv][l16 * 72 + 32 + quad * 8];
        f4 hw[4];
        #pragma unroll
        for (int t = 0; t < 4; t++) {
            hw[t] = f4{0.f,0.f,0.f,0.f};
            s8 b0 = *(const s8*)&WgT[(t * 16 + l16) * 72 + quad * 8];
            hw[t] = __builtin_amdgcn_mfma_f32_16x16x32_bf16(a0, b0, hw[t], 0, 0, 0);
            s8 b1_ = *(const s8*)&WgT[(t * 16 + l16) * 72 + 32 + quad * 8];
            hw[t] = __builtin_amdgcn_mfma_f32_16x16x32_bf16(a1, b1_, hw[t], 0, 0, 0);
        }
        #pragma unroll
        for (int t = 0; t < 4; t++) {
            int col = t * 16 + l16;
            float alv = al[col], arv = ar[col];
            #pragma unroll
            for (int r = 0; r < 4; r++) {
                int row = row0 + quad * 4 + r;
                float h = hw[t][r];
                P[(size_t)row * 64 + col] = bf16r(h) | (bf16r(vv[t][r]) << 16);
                float pl = h * alv, pr = h * arv;
                #pragma unroll
                for (int m = 1; m < 16; m <<= 1) {
                    pl += __shfl_xor(pl, m, 64);
                    pr += __shfl_xor(pr, m, 64);
                }
                if (l16 == 0) {
                    el[(size_t)row * 4 + t] = pl;
                    er[(size_t)row * 4 + t] = pr;
                }
            }
        }
    }
}

// ================= edge walk: 1 node/wave, exp once/edge, packed bf16 gather ======
template <int RELU>
__global__ void k_edges(const int* __restrict__ rows, const int* __restrict__ csr,
                        const unsigned* __restrict__ Pin,
                        const float* __restrict__ el, const float* __restrict__ er,
                        const float* __restrict__ gat_in, const float* __restrict__ gin_in,
                        const float* __restrict__ eps_p,
                        float* __restrict__ vgf, unsigned short* __restrict__ vgb,
                        unsigned short* __restrict__ xb) {
    __shared__ float ews[4][256];
    int wv = threadIdx.x >> 6, lane = threadIdx.x & 63;
    int n = blockIdx.x * 4 + wv;
    int st = rows[n], dg = rows[n + 1] - st;
    int hd = lane >> 4;
    float4 erv = *reinterpret_cast<const float4*>(er + (size_t)n * 4);
    float accg = 0.f, acci = 0.f, ssum = 0.f;
    for (int base = 0; base < dg; base += 64) {
        int rem = dg - base; if (rem > 64) rem = 64;
        int myi = 0;
        if (lane < rem) {
            myi = csr[st + base + lane];
            float4 lv = *reinterpret_cast<const float4*>(el + (size_t)myi * 4);
            float4 ev;
            ev.x = __expf(leaky(lv.x + erv.x));
            ev.y = __expf(leaky(lv.y + erv.y));
            ev.z = __expf(leaky(lv.z + erv.z));
            ev.w = __expf(leaky(lv.w + erv.w));
            *reinterpret_cast<float4*>(&ews[wv][lane * 4]) = ev;
        }
        int j = 0;
        for (; j + 4 <= rem; j += 4) {
            int s0 = __shfl(myi, j, 64),     s1 = __shfl(myi, j + 1, 64);
            int s2 = __shfl(myi, j + 2, 64), s3 = __shfl(myi, j + 3, 64);
            unsigned p0 = Pin[(size_t)s0 * 64 + lane];
            unsigned p1 = Pin[(size_t)s1 * 64 + lane];
            unsigned p2 = Pin[(size_t)s2 * 64 + lane];
            unsigned p3 = Pin[(size_t)s3 * 64 + lane];
            float a0 = ews[wv][(j + 0) * 4 + hd];
            float a1 = ews[wv][(j + 1) * 4 + hd];
            float a2 = ews[wv][(j + 2) * 4 + hd];
            float a3 = ews[wv][(j + 3) * 4 + hd];
            accg += a0 * lo16(p0) + a1 * lo16(p1) + a2 * lo16(p2) + a3 * lo16(p3);
            acci += hi16(p0) + hi16(p1) + hi16(p2) + hi16(p3);
            ssum += a0 + a1 + a2 + a3;
        }
        for (; j < rem; j++) {
            int s0 = __shfl(myi, j, 64);
            unsigned p0 = Pin[(size_t)s0 * 64 + lane];
            float a0 = ews[wv][j * 4 + hd];
            accg += a0 * lo16(p0); acci += hi16(p0); ssum += a0;
        }
    }
    float vg = accg / (ssum + 1e-9f) + gat_in[(size_t)n * 64 + lane];
    if (RELU) vg = fmaxf(vg, 0.f);
    float invd = 1.0f / fmaxf((float)dg, 1.0f);
    float x = (1.0f + eps_p[0]) * gin_in[(size_t)n * 64 + lane] + acci * invd;
    size_t off = (size_t)n * 64 + lane;
    vgf[off] = vg;
    vgb[off] = (unsigned short)bf16r(vg);
    xb[off] = (unsigned short)bf16r(x);
}

// ====== k_mlp: GIN 2-layer MLP (y1 in LDS) + (L==0: GAT-l1 pre fused) ======
template <int L>
__global__ __launch_bounds__(256) void k_mlp(const unsigned short* __restrict__ Gx,
        const unsigned short* __restrict__ Eb,
        const float* __restrict__ W1, const float* __restrict__ b1,
        const float* __restrict__ W2, const float* __restrict__ b2,
        const float* __restrict__ gatW, const float* __restrict__ al,
        const float* __restrict__ ar,
        unsigned short* __restrict__ Fb, float* __restrict__ Cf,
        unsigned* __restrict__ P, float* __restrict__ el, float* __restrict__ er) {
    __shared__ unsigned short W1T[64 * 72];
    __shared__ unsigned short W2T[64 * 72];
    __shared__ unsigned short WgT[(L == 0) ? 64 * 72 : 64];
    __shared__ unsigned short y1s[4][16 * 72];
    for (int idx = threadIdx.x; idx < 64 * 64; idx += 256) {
        int k = idx >> 6, n = idx & 63;
        W1T[n * 72 + k] = (unsigned short)bf16r(W1[idx]);
        W2T[n * 72 + k] = (unsigned short)bf16r(W2[idx]);
        if (L == 0) WgT[n * 72 + k] = (unsigned short)bf16r(gatW[idx]);
    }
    __syncthreads();
    int wv = threadIdx.x >> 6, lane = threadIdx.x & 63;
    int quad = lane >> 4, l16 = lane & 15;
    int gw = blockIdx.x * 4 + wv;
    int mtEnd = gw * 2 + 2; if (mtEnd > 3125) mtEnd = 3125;
    for (int mt = gw * 2; mt < mtEnd; mt++) {
        int row0 = mt * 16;
        const unsigned short* arow = Gx + (size_t)(row0 + l16) * 64;
        s8 a0 = *(const s8*)(arow + quad * 8);
        s8 a1 = *(const s8*)(arow + 32 + quad * 8);
        f4 acc1[4];
        #pragma unroll
        for (int t = 0; t < 4; t++) {
            acc1[t] = f4{0.f,0.f,0.f,0.f};
            s8 b0 = *(const s8*)&W1T[(t * 16 + l16) * 72 + quad * 8];
            acc1[t] = __builtin_amdgcn_mfma_f32_16x16x32_bf16(a0, b0, acc1[t], 0, 0, 0);
            s8 b1_ = *(const s8*)&W1T[(t * 16 + l16) * 72 + 32 + quad * 8];
            acc1[t] = __builtin_amdgcn_mfma_f32_16x16x32_bf16(a1, b1_, acc1[t], 0, 0, 0);
        }
        #pragma unroll
        for (int t = 0; t < 4; t++) {
            float b1v = b1[t * 16 + l16];
            #pragma unroll
            for (int r = 0; r < 4; r++) {
                float v = fmaxf(acc1[t][r] + b1v, 0.f);
                y1s[wv][(quad * 4 + r) * 72 + t * 16 + l16] = (unsigned short)bf16r(v);
            }
        }
        s8 c0 = *(const s8*)&y1s[wv][l16 * 72 + quad * 8];
        s8 c1 = *(const s8*)&y1s[wv][l16 * 72 + 32 + quad * 8];
        f4 acc2[4];
        #pragma unroll
        for (int t = 0; t < 4; t++) {
            acc2[t] = f4{0.f,0.f,0.f,0.f};
            s8 b0 = *(const s8*)&W2T[(t * 16 + l16) * 72 + quad * 8];
            acc2[t] = __builtin_amdgcn_mfma_f32_16x16x32_bf16(c0, b0, acc2[t], 0, 0, 0);
            s8 b1_ = *(const s8*)&W2T[(t * 16 + l16) * 72 + 32 + quad * 8];
            acc2[t] = __builtin_amdgcn_mfma_f32_16x16x32_bf16(c1, b1_, acc2[t], 0, 0, 0);
        }
        unsigned short vb[4][4];
        #pragma unroll
        for (int t = 0; t < 4; t++) {
            int col = t * 16 + l16;
            float b2v = b2[col];
            #pragma unroll
            for (int r = 0; r < 4; r++) {
                float v = acc2[t][r] + b2v;
                if (L == 0) v = fmaxf(v, 0.f);
                size_t off = (size_t)(row0 + quad * 4 + r) * 64 + col;
                unsigned short vb16 = (unsigned short)bf16r(v);
                vb[t][r] = vb16;
                Fb[off] = vb16;
                Cf[off] = v;
            }
        }
        if (L == 0) {
            // GAT-l1 pre: hW = vg(bf16, E) @ gatW ; pack with gin bf16
            const unsigned short* erow = Eb + (size_t)(row0 + l16) * 64;
            s8 e0 = *(const s8*)(erow + quad * 8);
            s8 e1 = *(const s8*)(erow + 32 + quad * 8);
            f4 hw[4];
            #pragma unroll
            for (int t = 0; t < 4; t++) {
                hw[t] = f4{0.f,0.f,0.f,0.f};
                s8 b0 = *(const s8*)&WgT[(t * 16 + l16) * 72 + quad * 8];
                hw[t] = __builtin_amdgcn_mfma_f32_16x16x32_bf16(e0, b0, hw[t], 0, 0, 0);
                s8 b1_ = *(const s8*)&WgT[(t * 16 + l16) * 72 + 32 + quad * 8];
                hw[t] = __builtin_amdgcn_mfma_f32_16x16x32_bf16(e1, b1_, hw[t], 0, 0, 0);
            }
            #pragma unroll
            for (int t = 0; t < 4; t++) {
                int col = t * 16 + l16;
                float alv = al[col], arv = ar[col];
                #pragma unroll
                for (int r = 0; r < 4; r++) {
                    int row = row0 + quad * 4 + r;
                    float h = hw[t][r];
                    P[(size_t)row * 64 + col] = bf16r(h) | ((unsigned)vb[t][r] << 16);
                    float pl = h * alv, pr = h * arv;
                    #pragma unroll
                    for (int m = 1; m < 16; m <<= 1) {
                        pl += __shfl_xor(pl, m, 64);
                        pr += __shfl_xor(pr, m, 64);
                    }
                    if (l16 == 0) {
                        el[(size_t)row * 4 + t] = pl;
                        er[(size_t)row * 4 + t] = pr;
                    }
                }
            }
        }
    }
}

// ========== k_route: fp32 LDS-tiled gating, 64 nodes/block, stats hierarchical ==========
__global__ __launch_bounds__(256) void k_route(const float* __restrict__ zg,
        const float* __restrict__ zi,
        const float* __restrict__ ggW, const float* __restrict__ ggb,
        const float* __restrict__ igW, const float* __restrict__ igb,
        float* __restrict__ wgtg, float* __restrict__ wgti,
        float* __restrict__ stats) {
    __shared__ float zs[64][65];
    __shared__ float gws[256];
    __shared__ float sstat[16];
    if (threadIdx.x < 16) sstat[threadIdx.x] = 0.f;
    int n0 = blockIdx.x * 64;
    int wv = threadIdx.x >> 6, lane = threadIdx.x & 63;
    for (int q = 0; q < 2; q++) {
        const float* Z = q ? zi : zg;
        const float* GW = q ? igW : ggW;
        const float* GB = q ? igb : ggb;
        gws[threadIdx.x] = GW[threadIdx.x];
        #pragma unroll
        for (int r = 0; r < 16; r++) {
            int row = wv * 16 + r;
            int n = n0 + row;
            zs[row][lane] = (n < NN) ? Z[(size_t)n * 64 + lane] : 0.f;
        }
        __syncthreads();
        int node = threadIdx.x >> 2, e = threadIdx.x & 3;
        float lg = GB[e];
        #pragma unroll 8
        for (int k = 0; k < 64; k++) lg += zs[node][k] * gws[k * 4 + e];
        float b = __shfl_xor(lg, 1, 64);
        float c = __shfl_xor(lg, 2, 64);
        float d = __shfl_xor(b, 2, 64);
        float arr[4];
        arr[e] = lg; arr[e ^ 1] = b; arr[e ^ 2] = c; arr[e ^ 3] = d;
        int n = n0 + node;
        if (e == 0 && n < NN) {
            float mx = fmaxf(fmaxf(arr[0], arr[1]), fmaxf(arr[2], arr[3]));
            float ex0 = __expf(arr[0] - mx), ex1 = __expf(arr[1] - mx);
            float ex2 = __expf(arr[2] - mx), ex3 = __expf(arr[3] - mx);
            float inv = 1.0f / (ex0 + ex1 + ex2 + ex3);
            float pr[4] = {ex0 * inv, ex1 * inv, ex2 * inv, ex3 * inv};
            int i1 = 0; float v1 = pr[0];
            #pragma unroll
            for (int t = 1; t < 4; t++) if (pr[t] > v1) { v1 = pr[t]; i1 = t; }
            int i2 = -1; float v2 = -1.f;
            #pragma unroll
            for (int t = 0; t < 4; t++) if (t != i1 && pr[t] > v2) { v2 = pr[t]; i2 = t; }
            float wsum = v1 + v2;
            float wq[4] = {0.f, 0.f, 0.f, 0.f};
            wq[i1] = v1 / wsum; wq[i2] = v2 / wsum;
            float* WD = q ? wgti : wgtg;
            *reinterpret_cast<float4*>(WD + (size_t)n * 4) = float4{wq[0], wq[1], wq[2], wq[3]};
            #pragma unroll
            for (int t = 0; t < 4; t++) atomicAdd(&sstat[q * 8 + t], pr[t]);
            atomicAdd(&sstat[q * 8 + 4 + i1], 1.f);
            atomicAdd(&sstat[q * 8 + 4 + i2], 1.f);
        }
        __syncthreads();
    }
    if (threadIdx.x < 16) atomicAdd(&stats[threadIdx.x], sstat[threadIdx.x]);
}

// ======= dense-all experts (MFMA), both problems in one grid =======
__global__ __launch_bounds__(256) void k_expert(const unsigned short* __restrict__ Eb,
        const unsigned short* __restrict__ Fb,
        const float* __restrict__ g_eW1, const float* __restrict__ g_eb1,
        const float* __restrict__ g_eW2, const float* __restrict__ g_eb2,
        const float* __restrict__ i_eW1, const float* __restrict__ i_eb1,
        const float* __restrict__ i_eW2, const float* __restrict__ i_eb2,
        const float* __restrict__ wgtg, const float* __restrict__ wgti,
        float* __restrict__ moegf, float* __restrict__ moeif,
        unsigned short* __restrict__ ub) {
    __shared__ unsigned short w1t[4 * 32 * 72];
    __shared__ unsigned short w2t[4 * 64 * 40];
    __shared__ unsigned short y1s[4][16 * 40];
    int p = (blockIdx.x >= NBE) ? 1 : 0;
    int bb = blockIdx.x - p * NBE;
    const unsigned short* Ab = p ? Fb : Eb;
    const float* eW1 = p ? i_eW1 : g_eW1;
    const float* eb1 = p ? i_eb1 : g_eb1;
    const float* eW2 = p ? i_eW2 : g_eW2;
    const float* eb2 = p ? i_eb2 : g_eb2;
    const float* wgt = p ? wgti : wgtg;
    float* moef = p ? moeif : moegf;
    int qoff = p ? 64 : 0;
    for (int g = threadIdx.x; g < 8192; g += 256) {
        int e = g >> 11, rem = g & 2047;
        int k = rem >> 5, n = rem & 31;
        w1t[e * 2304 + n * 72 + k] = (unsigned short)bf16r(eW1[g]);
    }
    for (int g = threadIdx.x; g < 8192; g += 256) {
        int e = g >> 11, rem = g & 2047;
        int k = rem >> 6, n = rem & 63;
        w2t[e * 2560 + n * 40 + k] = (unsigned short)bf16r(eW2[g]);
    }
    __syncthreads();
    int wv = threadIdx.x >> 6, lane = threadIdx.x & 63;
    int quad = lane >> 4, l16 = lane & 15;
    int gw = bb * 4 + wv;
    int mtEnd = gw * 4 + 4; if (mtEnd > 3125) mtEnd = 3125;
    for (int mt = gw * 4; mt < mtEnd; mt++) {
        int row0 = mt * 16;
        const unsigned short* arow = Ab + (size_t)(row0 + l16) * 64;
        s8 a0 = *(const s8*)(arow + quad * 8);
        s8 a1 = *(const s8*)(arow + 32 + quad * 8);
        f4 outacc[4];
        #pragma unroll
        for (int t = 0; t < 4; t++) outacc[t] = f4{0.f,0.f,0.f,0.f};
        for (int e = 0; e < 4; e++) {
            f4 acc1[2];
            #pragma unroll
            for (int t = 0; t < 2; t++) {
                acc1[t] = f4{0.f,0.f,0.f,0.f};
                s8 b0 = *(const s8*)&w1t[e * 2304 + (t * 16 + l16) * 72 + quad * 8];
                acc1[t] = __builtin_amdgcn_mfma_f32_16x16x32_bf16(a0, b0, acc1[t], 0, 0, 0);
                s8 b1_ = *(const s8*)&w1t[e * 2304 + (t * 16 + l16) * 72 + 32 + quad * 8];
                acc1[t] = __builtin_amdgcn_mfma_f32_16x16x32_bf16(a1, b1_, acc1[t], 0, 0, 0);
            }
            #pragma unroll
            for (int t = 0; t < 2; t++) {
                float b1v = eb1[e * 32 + t * 16 + l16];
                #pragma unroll
                for (int r = 0; r < 4; r++) {
                    float v = fmaxf(acc1[t][r] + b1v, 0.f);
                    y1s[wv][(quad * 4 + r) * 40 + t * 16 + l16] = (unsigned short)bf16r(v);
                }
            }
            s8 a2 = *(const s8*)&y1s[wv][l16 * 40 + quad * 8];
            f4 acc2[4];
            #pragma unroll
            for (int t = 0; t < 4; t++) {
                acc2[t] = f4{0.f,0.f,0.f,0.f};
                s8 b2_ = *(const s8*)&w2t[e * 2560 + (t * 16 + l16) * 40 + quad * 8];
                acc2[t] = __builtin_amdgcn_mfma_f32_16x16x32_bf16(a2, b2_, acc2[t], 0, 0, 0);
            }
            #pragma unroll
            for (int t = 0; t < 4; t++) {
                float b2v = eb2[e * 64 + t * 16 + l16];
                #pragma unroll
                for (int r = 0; r < 4; r++) {
                    float we = wgt[(size_t)(row0 + quad * 4 + r) * 4 + e];
                    outacc[t][r] += we * (acc2[t][r] + b2v);
                }
            }
        }
        #pragma unroll
        for (int t = 0; t < 4; t++) {
            int col = t * 16 + l16;
            #pragma unroll
            for (int r = 0; r < 4; r++) {
                int row = row0 + quad * 4 + r;
                float v = outacc[t][r];
                moef[(size_t)row * 64 + col] = v;
                ub[(size_t)row * 128 + qoff + col] = (unsigned short)bf16r(v);
            }
        }
    }
}

// ================= fusion gate (MFMA) + aux finalize (block 0) =================
__global__ __launch_bounds__(256) void k_fusion(const unsigned short* __restrict__ ubuf,
        const float* __restrict__ W1, const float* __restrict__ b1,
        const float* __restrict__ W2, const float* __restrict__ b2,
        const float* __restrict__ moegf, const float* __restrict__ moeif,
        float* __restrict__ out, const float* __restrict__ stats) {
    __shared__ unsigned short W1T[64 * 136];
    __shared__ unsigned short W2T[64 * 72];
    __shared__ unsigned short y1s[4][16 * 72];
    for (int idx = threadIdx.x; idx < 128 * 64; idx += 256) {
        int k = idx >> 6, n = idx & 63;
        W1T[n * 136 + k] = (unsigned short)bf16r(W1[idx]);
    }
    for (int idx = threadIdx.x; idx < 64 * 64; idx += 256) {
        int k = idx >> 6, n = idx & 63;
        W2T[n * 72 + k] = (unsigned short)bf16r(W2[idx]);
    }
    __syncthreads();
    int wv = threadIdx.x >> 6, lane = threadIdx.x & 63;
    int quad = lane >> 4, l16 = lane & 15;
    int gw = blockIdx.x * 4 + wv;
    int mtEnd = gw * 2 + 2; if (mtEnd > 3125) mtEnd = 3125;
    for (int mt = gw * 2; mt < mtEnd; mt++) {
        int row0 = mt * 16;
        const unsigned short* arow = ubuf + (size_t)(row0 + l16) * 128;
        f4 acc1[4];
        #pragma unroll
        for (int t = 0; t < 4; t++) acc1[t] = f4{0.f,0.f,0.f,0.f};
        #pragma unroll
        for (int ks = 0; ks < 4; ks++) {
            s8 a = *(const s8*)(arow + ks * 32 + quad * 8);
            #pragma unroll
            for (int t = 0; t < 4; t++) {
                s8 b = *(const s8*)&W1T[(t * 16 + l16) * 136 + ks * 32 + quad * 8];
                acc1[t] = __builtin_amdgcn_mfma_f32_16x16x32_bf16(a, b, acc1[t], 0, 0, 0);
            }
        }
        #pragma unroll
        for (int t = 0; t < 4; t++) {
            float b1v = b1[t * 16 + l16];
            #pragma unroll
            for (int r = 0; r < 4; r++) {
                float v = fmaxf(acc1[t][r] + b1v, 0.f);
                y1s[wv][(quad * 4 + r) * 72 + t * 16 + l16] = (unsigned short)bf16r(v);
            }
        }
        f4 acc2[4];
        #pragma unroll
        for (int t = 0; t < 4; t++) acc2[t] = f4{0.f,0.f,0.f,0.f};
        #pragma unroll
        for (int ks = 0; ks < 2; ks++) {
            s8 a = *(const s8*)&y1s[wv][l16 * 72 + ks * 32 + quad * 8];
            #pragma unroll
            for (int t = 0; t < 4; t++) {
                s8 b = *(const s8*)&W2T[(t * 16 + l16) * 72 + ks * 32 + quad * 8];
                acc2[t] = __builtin_amdgcn_mfma_f32_16x16x32_bf16(a, b, acc2[t], 0, 0, 0);
            }
        }
        #pragma unroll
        for (int t = 0; t < 4; t++) {
            int col = t * 16 + l16;
            float b2v = b2[col];
            #pragma unroll
            for (int r = 0; r < 4; r++) {
                int row = row0 + quad * 4 + r;
                float g = 1.0f / (1.0f + __expf(-(acc2[t][r] + b2v)));
                float zgv = moegf[(size_t)row * 64 + col];
                float ziv = moeif[(size_t)row * 64 + col];
                out[(size_t)row * 64 + col] = g * zgv * ziv + (1.0f - g) * g;
            }
        }
    }
    // aux finalize on block 0
    if (blockIdx.x == 0 && threadIdx.x < 64) {
        int t = threadIdx.x;
        float s = (t < 16) ? stats[t] : 0.f;
        float aux = 0.f;
        for (int q = 0; q < 2; q++) {
            float a = 0.f;
            for (int e = 0; e < 4; e++) {
                float pr = __shfl(s, q * 8 + e, 64);
                float f  = __shfl(s, q * 8 + 4 + e, 64);
                a += (f / (float)NN) * (pr / (float)NN);
            }
            aux += 4.0f * a;
        }
        if (t == 0) out[(size_t)NN * 64] = aux;
    }
}

extern "C" void kernel_launch(void* const* d_in, const int* in_sizes, int n_in,
                              void* d_out, int out_size, void* d_ws, size_t ws_size,
                              hipStream_t stream) {
    (void)in_sizes; (void)n_in; (void)out_size; (void)ws_size;
    const float* features  = (const float*)d_in[0];
    const int*   node_types= (const int*)d_in[1];
    const int*   src       = (const int*)d_in[2];
    const int*   dst       = (const int*)d_in[3];
    const float* W_person  = (const float*)d_in[4];
    const float* b_person  = (const float*)d_in[5];
    const float* W_disease = (const float*)d_in[6];
    const float* b_disease = (const float*)d_in[7];
    const float* gat_W     = (const float*)d_in[8];
    const float* gat_al    = (const float*)d_in[9];
    const float* gat_ar    = (const float*)d_in[10];
    const float* gin_eps   = (const float*)d_in[11];
    const float* gin_W1    = (const float*)d_in[12];
    const float* gin_b1    = (const float*)d_in[13];
    const float* gin_W2    = (const float*)d_in[14];
    const float* gin_b2    = (const float*)d_in[15];
    const float* gat_gW    = (const float*)d_in[16];
    const float* gat_gb    = (const float*)d_in[17];
    const float* gat_eW1   = (const float*)d_in[18];
    const float* gat_eb1   = (const float*)d_in[19];
    const float* gat_eW2   = (const float*)d_in[20];
    const float* gat_eb2   = (const float*)d_in[21];
    const float* gin_gW    = (const float*)d_in[22];
    const float* gin_gb    = (const float*)d_in[23];
    const float* gin_eW1   = (const float*)d_in[24];
    const float* gin_eb1   = (const float*)d_in[25];
    const float* gin_eW2   = (const float*)d_in[26];
    const float* gin_eb2   = (const float*)d_in[27];
    const float* fg_W1     = (const float*)d_in[28];
    const float* fg_b1     = (const float*)d_in[29];
    const float* fg_W2     = (const float*)d_in[30];
    const float* fg_b2     = (const float*)d_in[31];
    float* out = (float*)d_out;

    float* ws = (float*)d_ws;
    size_t o = 0;
    float* A = ws + o; o += (size_t)NN * 64;        // h0f; later ub (bf16 NN x 128)
    float* B = ws + o; o += (size_t)NN * 64;        // vg f32 chain; later moegf
    float* C = ws + o; o += (size_t)NN * 64;        // gin f32 chain; later moeif
    unsigned short* E  = (unsigned short*)(ws + o); o += (size_t)NN * 32;  // vgb
    unsigned short* F  = (unsigned short*)(ws + o); o += (size_t)NN * 32;  // ginb
    unsigned short* G  = (unsigned short*)(ws + o); o += (size_t)NN * 32;  // xb
    unsigned* P = (unsigned*)(ws + o); o += (size_t)NN * 64;  // packed hW|gin
    float* el = ws + o; o += (size_t)NN * 4;
    float* er = ws + o; o += (size_t)NN * 4;
    float* wgtg = ws + o; o += (size_t)NN * 4;
    float* wgti = ws + o; o += (size_t)NN * 4;
    float* stats = ws + o; o += 16;
    int* degcnt    = (int*)(ws + o); o += NN;
    int* row_start = (int*)(ws + o); o += NN + 4;
    int* cursor    = (int*)(ws + o); o += NN;
    int* bsums     = (int*)(ws + o); o += 256;
    int* bpre      = (int*)(ws + o); o += 256;
    int* csr_src   = (int*)(ws + o); o += EE;

    unsigned short* ub = (unsigned short*)A;  // reuse after edges(l0)

    const int NB_edge = EE / 256;   // 3125
    const int NB_node = NN / 4;     // 12500

    hipMemsetAsync(degcnt, 0, sizeof(int) * NN, stream);
    hipMemsetAsync(stats, 0, sizeof(float) * 16, stream);

    // CSR build
    k_deg<<<NB_edge, 256, 0, stream>>>(dst, degcnt);
    k_scan_a<<<NBLK_SCAN, 256, 0, stream>>>(degcnt, bsums);
    k_scan_b<<<1, 256, 0, stream>>>(bsums, bpre);
    k_scan_c<<<NBLK_SCAN, 256, 0, stream>>>(degcnt, bpre, row_start, cursor);
    k_fill<<<NB_edge, 256, 0, stream>>>(src, dst, cursor, csr_src);

    // projection + GAT-l0 pre
    k_pre<<<NBG, 256, 0, stream>>>(features, node_types, W_person, b_person,
                                   W_disease, b_disease, gat_W, gat_al, gat_ar,
                                   A, P, el, er);

    // ---- layer 0 ----
    k_edges<1><<<NB_node, 256, 0, stream>>>(row_start, csr_src, P, el, er, A, A,
                                            gin_eps, B, E, G);
    k_mlp<0><<<NBG, 256, 0, stream>>>(G, E, gin_W1, gin_b1, gin_W2, gin_b2,
                                      gat_W + 4096, gat_al + 64, gat_ar + 64,
                                      F, C, P, el, er);

    // ---- layer 1 ----
    k_edges<0><<<NB_node, 256, 0, stream>>>(row_start, csr_src, P, el, er, B, C,
                                            gin_eps + 1, B, E, G);
    k_mlp<1><<<NBG, 256, 0, stream>>>(G, nullptr, gin_W1 + 4096, gin_b1 + 64,
                                      gin_W2 + 4096, gin_b2 + 64,
                                      nullptr, nullptr, nullptr,
                                      F, C, nullptr, nullptr, nullptr);

    // ---- MoE: routing (fp32) + dense-all experts ----
    k_route<<<RBLK, 256, 0, stream>>>(B, C, gat_gW, gat_gb, gin_gW, gin_gb,
                                      wgtg, wgti, stats);
    k_expert<<<NBE * 2, 256, 0, stream>>>(E, F,
                                          gat_eW1, gat_eb1, gat_eW2, gat_eb2,
                                          gin_eW1, gin_eb1, gin_eW2, gin_eb2,
                                          wgtg, wgti, B, C, ub);

    // ---- fusion + aux ----
    k_fusion<<<NBG, 256, 0, stream>>>(ub, fg_W1, fg_b1, fg_W2, fg_b2, B, C, out, stats);
}

// Round 8
// 367.675 us; speedup vs baseline: 8.5504x; 1.1204x over previous
//
#include <hip/hip_runtime.h>

#define NN 50000
#define EE 800000
#define NEG 0.2f
#define NBLK_SCAN 196   // ceil(NN/256)
#define NBG 391         // gemm grid: 1564 waves x 2 mtiles >= 3125
#define NBE 196         // expert grid: 784 waves x 4 mtiles >= 3125
#define RBLK 782        // route grid: 64 nodes/block
#define NBKT 98         // dst buckets of 512
#define BCAP 9216       // bucket capacity (mean 8192 + 11 sigma)
#define EPB 2048        // edges per binA block
#define NBINA 391       // ceil(EE/EPB)

typedef __attribute__((ext_vector_type(8))) short s8;
typedef __attribute__((ext_vector_type(4))) float f4;

__device__ __forceinline__ float leaky(float x) { return x > 0.f ? x : NEG * x; }
__device__ __forceinline__ unsigned bf16r(float x) {
    unsigned u = __float_as_uint(x);
    return (u + 0x7fffu + ((u >> 16) & 1u)) >> 16;
}
__device__ __forceinline__ float lo16(unsigned p) { return __uint_as_float(p << 16); }
__device__ __forceinline__ float hi16(unsigned p) { return __uint_as_float(p & 0xffff0000u); }

__device__ __forceinline__ s8 a_from_f32(const float* p) {
    float4 u = *reinterpret_cast<const float4*>(p);
    float4 v = *reinterpret_cast<const float4*>(p + 4);
    s8 r;
    r[0] = (short)bf16r(u.x); r[1] = (short)bf16r(u.y);
    r[2] = (short)bf16r(u.z); r[3] = (short)bf16r(u.w);
    r[4] = (short)bf16r(v.x); r[5] = (short)bf16r(v.y);
    r[6] = (short)bf16r(v.z); r[7] = (short)bf16r(v.w);
    return r;
}

// ======== binA: bucket edges by dst>>9, also accumulate degcnt ========
__global__ __launch_bounds__(256) void k_binA(const int* __restrict__ src,
        const int* __restrict__ dst, int* __restrict__ degcnt,
        int* __restrict__ bktcnt, unsigned* __restrict__ bkt) {
    __shared__ int cnt[NBKT];
    __shared__ int base[NBKT];
    for (int i = threadIdx.x; i < NBKT; i += 256) cnt[i] = 0;
    __syncthreads();
    int e0 = blockIdx.x * EPB;
    int d[8], s[8];
    #pragma unroll
    for (int i = 0; i < 8; i++) {
        int e = e0 + i * 256 + threadIdx.x;
        if (e < EE) {
            d[i] = dst[e]; s[i] = src[e];
            atomicAdd(&degcnt[d[i]], 1);
            atomicAdd(&cnt[d[i] >> 9], 1);
        } else d[i] = -1;
    }
    __syncthreads();
    for (int i = threadIdx.x; i < NBKT; i += 256)
        base[i] = atomicAdd(&bktcnt[i], cnt[i]);
    __syncthreads();
    for (int i = threadIdx.x; i < NBKT; i += 256) cnt[i] = 0;
    __syncthreads();
    #pragma unroll
    for (int i = 0; i < 8; i++) {
        if (d[i] >= 0) {
            int b = d[i] >> 9;
            int p = base[b] + atomicAdd(&cnt[b], 1);
            if (p < BCAP)
                bkt[(size_t)b * BCAP + p] = ((unsigned)s[i] << 9) | (unsigned)(d[i] & 511);
        }
    }
}

// ================= scans =================
__global__ void k_scan_a(const int* __restrict__ degcnt, int* __restrict__ bsums) {
    __shared__ int sm[4];
    int i = blockIdx.x * 256 + threadIdx.x;
    int v = (i < NN) ? degcnt[i] : 0;
    #pragma unroll
    for (int o = 1; o < 64; o <<= 1) v += __shfl_xor(v, o, 64);
    if ((threadIdx.x & 63) == 0) sm[threadIdx.x >> 6] = v;
    __syncthreads();
    if (threadIdx.x == 0) bsums[blockIdx.x] = sm[0] + sm[1] + sm[2] + sm[3];
}

__global__ void k_scan_b(const int* __restrict__ bsums, int* __restrict__ bpre) {
    __shared__ int sm[256];
    int t = threadIdx.x;
    sm[t] = (t < NBLK_SCAN) ? bsums[t] : 0;
    __syncthreads();
    for (int off = 1; off < 256; off <<= 1) {
        int u = (t >= off) ? sm[t - off] : 0;
        __syncthreads();
        sm[t] += u;
        __syncthreads();
    }
    if (t < NBLK_SCAN) bpre[t] = (t == 0) ? 0 : sm[t - 1];
}

__global__ void k_scan_c(const int* __restrict__ degcnt, const int* __restrict__ bpre,
                         int* __restrict__ row_start) {
    __shared__ int sm[256];
    int t = threadIdx.x;
    int i = blockIdx.x * 256 + t;
    int v = (i < NN) ? degcnt[i] : 0;
    sm[t] = v;
    __syncthreads();
    for (int off = 1; off < 256; off <<= 1) {
        int u = (t >= off) ? sm[t - off] : 0;
        __syncthreads();
        sm[t] += u;
        __syncthreads();
    }
    int incl = sm[t];
    if (i < NN) row_start[i] = bpre[blockIdx.x] + incl - v;
    if (i == NN - 1) row_start[NN] = bpre[blockIdx.x] + incl;
}

// ======= fused: blocks [0,NBKT) = binB CSR fill; blocks [NBKT,..) = projection+GAT-l0 pre =======
__global__ __launch_bounds__(256) void k_binB_pre(
        const int* __restrict__ row_start, const int* __restrict__ bktcnt,
        const unsigned* __restrict__ bkt, int* __restrict__ csr_src,
        const float* __restrict__ feat, const int* __restrict__ types,
        const float* __restrict__ Wp, const float* __restrict__ bp,
        const float* __restrict__ Wd, const float* __restrict__ bd,
        const float* __restrict__ gW, const float* __restrict__ al,
        const float* __restrict__ ar,
        float* __restrict__ h0f, unsigned* __restrict__ P,
        float* __restrict__ el, float* __restrict__ er) {
    __shared__ unsigned short WpT[64 * 136];
    __shared__ unsigned short WdT[64 * 72];
    __shared__ unsigned short WgT[64 * 72];
    __shared__ unsigned short y0s[4][16 * 72];
    __shared__ int kur[512];
    if (blockIdx.x < NBKT) {
        // ---- binB: own one bucket, LDS cursors ----
        int b = blockIdx.x;
        int d0 = b << 9;
        for (int i = threadIdx.x; i < 512; i += 256) {
            int d = d0 + i;
            kur[i] = (d < NN) ? row_start[d] : 0;
        }
        __syncthreads();
        int cnt = bktcnt[b]; if (cnt > BCAP) cnt = BCAP;
        for (int i = threadIdx.x; i < cnt; i += 256) {
            unsigned v = bkt[(size_t)b * BCAP + i];
            int p = atomicAdd(&kur[v & 511], 1);
            csr_src[p] = (int)(v >> 9);
        }
        return;
    }
    // ---- projection + GAT-l0 pre (MFMA) ----
    for (int idx = threadIdx.x; idx < 128 * 64; idx += 256) {
        int k = idx >> 6, n = idx & 63;
        WpT[n * 136 + k] = (unsigned short)bf16r(Wp[idx]);
    }
    for (int idx = threadIdx.x; idx < 64 * 64; idx += 256) {
        int k = idx >> 6, n = idx & 63;
        WdT[n * 72 + k] = (unsigned short)bf16r(Wd[idx]);
        WgT[n * 72 + k] = (unsigned short)bf16r(gW[idx]);
    }
    __syncthreads();
    int wv = threadIdx.x >> 6, lane = threadIdx.x & 63;
    int quad = lane >> 4, l16 = lane & 15;
    int gw2 = (blockIdx.x - NBKT) * 4 + wv;
    int mtEnd = gw2 * 2 + 2; if (mtEnd > 3125) mtEnd = 3125;
    for (int mt = gw2 * 2; mt < mtEnd; mt++) {
        int row0 = mt * 16;
        const float* arow = feat + (size_t)(row0 + l16) * 128;
        f4 accp[4], accd[4];
        #pragma unroll
        for (int t = 0; t < 4; t++) { accp[t] = f4{0.f,0.f,0.f,0.f}; accd[t] = f4{0.f,0.f,0.f,0.f}; }
        #pragma unroll
        for (int ks = 0; ks < 4; ks++) {
            s8 a = a_from_f32(arow + ks * 32 + quad * 8);
            #pragma unroll
            for (int t = 0; t < 4; t++) {
                s8 b = *(const s8*)&WpT[(t * 16 + l16) * 136 + ks * 32 + quad * 8];
                accp[t] = __builtin_amdgcn_mfma_f32_16x16x32_bf16(a, b, accp[t], 0, 0, 0);
                if (ks < 2) {
                    s8 bd_ = *(const s8*)&WdT[(t * 16 + l16) * 72 + ks * 32 + quad * 8];
                    accd[t] = __builtin_amdgcn_mfma_f32_16x16x32_bf16(a, bd_, accd[t], 0, 0, 0);
                }
            }
        }
        int ty[4];
        #pragma unroll
        for (int r = 0; r < 4; r++) ty[r] = types[row0 + quad * 4 + r];
        float vv[4][4];
        #pragma unroll
        for (int t = 0; t < 4; t++) {
            int col = t * 16 + l16;
            float bpv = bp[col], bdv = bd[col];
            #pragma unroll
            for (int r = 0; r < 4; r++) {
                float v = ty[r] ? (accd[t][r] + bdv) : (accp[t][r] + bpv);
                vv[t][r] = v;
                h0f[(size_t)(row0 + quad * 4 + r) * 64 + col] = v;
                y0s[wv][(quad * 4 + r) * 72 + col] = (unsigned short)bf16r(v);
            }
        }
        s8 a0 = *(const s8*)&y0s[wv][l16 * 72 + quad * 8];
        s8 a1 = *(const s8*)&y0s[wv][l16 * 72 + 32 + quad * 8];
        f4 hw[4];
        #pragma unroll
        for (int t = 0; t < 4; t++) {
            hw[t] = f4{0.f,0.f,0.f,0.f};
            s8 b0 = *(const s8*)&WgT[(t * 16 + l16) * 72 + quad * 8];
            hw[t] = __builtin_amdgcn_mfma_f32_16x16x32_bf16(a0, b0, hw[t], 0, 0, 0);
            s8 b1_ = *(const s8*)&WgT[(t * 16 + l16) * 72 + 32 + quad * 8];
            hw[t] = __builtin_amdgcn_mfma_f32_16x16x32_bf16(a1, b1_, hw[t], 0, 0, 0);
        }
        #pragma unroll
        for (int t = 0; t < 4; t++) {
            int col = t * 16 + l16;
            float alv = al[col], arv = ar[col];
            #pragma unroll
            for (int r = 0; r < 4; r++) {
                int row = row0 + quad * 4 + r;
                float h = hw[t][r];
                P[(size_t)row * 64 + col] = bf16r(h) | (bf16r(vv[t][r]) << 16);
                float pl = h * alv, pr = h * arv;
                #pragma unroll
                for (int m = 1; m < 16; m <<= 1) {
                    pl += __shfl_xor(pl, m, 64);
                    pr += __shfl_xor(pr, m, 64);
                }
                if (l16 == 0) {
                    el[(size_t)row * 4 + t] = pl;
                    er[(size_t)row * 4 + t] = pr;
                }
            }
        }
    }
}

// ================= edge walk: 1 node/wave, exp once/edge, packed bf16 gather ======
template <int RELU>
__global__ void k_edges(const int* __restrict__ rows, const int* __restrict__ csr,
                        const unsigned* __restrict__ Pin,
                        const float* __restrict__ el, const float* __restrict__ er,
                        const float* __restrict__ gat_in, const float* __restrict__ gin_in,
                        const float* __restrict__ eps_p,
                        float* __restrict__ vgf, unsigned short* __restrict__ vgb,
                        unsigned short* __restrict__ xb) {
    __shared__ float ews[4][256];
    int wv = threadIdx.x >> 6, lane = threadIdx.x & 63;
    int n = blockIdx.x * 4 + wv;
    int st = rows[n], dg = rows[n + 1] - st;
    int hd = lane >> 4;
    float4 erv = *reinterpret_cast<const float4*>(er + (size_t)n * 4);
    float accg = 0.f, acci = 0.f, ssum = 0.f;
    for (int base = 0; base < dg; base += 64) {
        int rem = dg - base; if (rem > 64) rem = 64;
        int myi = 0;
        if (lane < rem) {
            myi = csr[st + base + lane];
            float4 lv = *reinterpret_cast<const float4*>(el + (size_t)myi * 4);
            float4 ev;
            ev.x = __expf(leaky(lv.x + erv.x));
            ev.y = __expf(leaky(lv.y + erv.y));
            ev.z = __expf(leaky(lv.z + erv.z));
            ev.w = __expf(leaky(lv.w + erv.w));
            *reinterpret_cast<float4*>(&ews[wv][lane * 4]) = ev;
        }
        int j = 0;
        for (; j + 4 <= rem; j += 4) {
            int s0 = __shfl(myi, j, 64),     s1 = __shfl(myi, j + 1, 64);
            int s2 = __shfl(myi, j + 2, 64), s3 = __shfl(myi, j + 3, 64);
            unsigned p0 = Pin[(size_t)s0 * 64 + lane];
            unsigned p1 = Pin[(size_t)s1 * 64 + lane];
            unsigned p2 = Pin[(size_t)s2 * 64 + lane];
            unsigned p3 = Pin[(size_t)s3 * 64 + lane];
            float a0 = ews[wv][(j + 0) * 4 + hd];
            float a1 = ews[wv][(j + 1) * 4 + hd];
            float a2 = ews[wv][(j + 2) * 4 + hd];
            float a3 = ews[wv][(j + 3) * 4 + hd];
            accg += a0 * lo16(p0) + a1 * lo16(p1) + a2 * lo16(p2) + a3 * lo16(p3);
            acci += hi16(p0) + hi16(p1) + hi16(p2) + hi16(p3);
            ssum += a0 + a1 + a2 + a3;
        }
        for (; j < rem; j++) {
            int s0 = __shfl(myi, j, 64);
            unsigned p0 = Pin[(size_t)s0 * 64 + lane];
            float a0 = ews[wv][j * 4 + hd];
            accg += a0 * lo16(p0); acci += hi16(p0); ssum += a0;
        }
    }
    float vg = accg / (ssum + 1e-9f) + gat_in[(size_t)n * 64 + lane];
    if (RELU) vg = fmaxf(vg, 0.f);
    float invd = 1.0f / fmaxf((float)dg, 1.0f);
    float x = (1.0f + eps_p[0]) * gin_in[(size_t)n * 64 + lane] + acci * invd;
    size_t off = (size_t)n * 64 + lane;
    vgf[off] = vg;
    vgb[off] = (unsigned short)bf16r(vg);
    xb[off] = (unsigned short)bf16r(x);
}

// ====== k_mlp: GIN 2-layer MLP (y1 in LDS) + (L==0: GAT-l1 pre fused) ======
template <int L>
__global__ __launch_bounds__(256) void k_mlp(const unsigned short* __restrict__ Gx,
        const unsigned short* __restrict__ Eb,
        const float* __restrict__ W1, const float* __restrict__ b1,
        const float* __restrict__ W2, const float* __restrict__ b2,
        const float* __restrict__ gatW, const float* __restrict__ al,
        const float* __restrict__ ar,
        unsigned short* __restrict__ Fb, float* __restrict__ Cf,
        unsigned* __restrict__ P, float* __restrict__ el, float* __restrict__ er) {
    __shared__ unsigned short W1T[64 * 72];
    __shared__ unsigned short W2T[64 * 72];
    __shared__ unsigned short WgT[(L == 0) ? 64 * 72 : 64];
    __shared__ unsigned short y1s[4][16 * 72];
    for (int idx = threadIdx.x; idx < 64 * 64; idx += 256) {
        int k = idx >> 6, n = idx & 63;
        W1T[n * 72 + k] = (unsigned short)bf16r(W1[idx]);
        W2T[n * 72 + k] = (unsigned short)bf16r(W2[idx]);
        if (L == 0) WgT[n * 72 + k] = (unsigned short)bf16r(gatW[idx]);
    }
    __syncthreads();
    int wv = threadIdx.x >> 6, lane = threadIdx.x & 63;
    int quad = lane >> 4, l16 = lane & 15;
    int gw = blockIdx.x * 4 + wv;
    int mtEnd = gw * 2 + 2; if (mtEnd > 3125) mtEnd = 3125;
    for (int mt = gw * 2; mt < mtEnd; mt++) {
        int row0 = mt * 16;
        const unsigned short* arow = Gx + (size_t)(row0 + l16) * 64;
        s8 a0 = *(const s8*)(arow + quad * 8);
        s8 a1 = *(const s8*)(arow + 32 + quad * 8);
        f4 acc1[4];
        #pragma unroll
        for (int t = 0; t < 4; t++) {
            acc1[t] = f4{0.f,0.f,0.f,0.f};
            s8 b0 = *(const s8*)&W1T[(t * 16 + l16) * 72 + quad * 8];
            acc1[t] = __builtin_amdgcn_mfma_f32_16x16x32_bf16(a0, b0, acc1[t], 0, 0, 0);
            s8 b1_ = *(const s8*)&W1T[(t * 16 + l16) * 72 + 32 + quad * 8];
            acc1[t] = __builtin_amdgcn_mfma_f32_16x16x32_bf16(a1, b1_, acc1[t], 0, 0, 0);
        }
        #pragma unroll
        for (int t = 0; t < 4; t++) {
            float b1v = b1[t * 16 + l16];
            #pragma unroll
            for (int r = 0; r < 4; r++) {
                float v = fmaxf(acc1[t][r] + b1v, 0.f);
                y1s[wv][(quad * 4 + r) * 72 + t * 16 + l16] = (unsigned short)bf16r(v);
            }
        }
        s8 c0 = *(const s8*)&y1s[wv][l16 * 72 + quad * 8];
        s8 c1 = *(const s8*)&y1s[wv][l16 * 72 + 32 + quad * 8];
        f4 acc2[4];
        #pragma unroll
        for (int t = 0; t < 4; t++) {
            acc2[t] = f4{0.f,0.f,0.f,0.f};
            s8 b0 = *(const s8*)&W2T[(t * 16 + l16) * 72 + quad * 8];
            acc2[t] = __builtin_amdgcn_mfma_f32_16x16x32_bf16(c0, b0, acc2[t], 0, 0, 0);
            s8 b1_ = *(const s8*)&W2T[(t * 16 + l16) * 72 + 32 + quad * 8];
            acc2[t] = __builtin_amdgcn_mfma_f32_16x16x32_bf16(c1, b1_, acc2[t], 0, 0, 0);
        }
        unsigned short vb[4][4];
        #pragma unroll
        for (int t = 0; t < 4; t++) {
            int col = t * 16 + l16;
            float b2v = b2[col];
            #pragma unroll
            for (int r = 0; r < 4; r++) {
                float v = acc2[t][r] + b2v;
                if (L == 0) v = fmaxf(v, 0.f);
                size_t off = (size_t)(row0 + quad * 4 + r) * 64 + col;
                unsigned short vb16 = (unsigned short)bf16r(v);
                vb[t][r] = vb16;
                Fb[off] = vb16;
                Cf[off] = v;
            }
        }
        if (L == 0) {
            const unsigned short* erow = Eb + (size_t)(row0 + l16) * 64;
            s8 e0 = *(const s8*)(erow + quad * 8);
            s8 e1 = *(const s8*)(erow + 32 + quad * 8);
            f4 hw[4];
            #pragma unroll
            for (int t = 0; t < 4; t++) {
                hw[t] = f4{0.f,0.f,0.f,0.f};
                s8 b0 = *(const s8*)&WgT[(t * 16 + l16) * 72 + quad * 8];
                hw[t] = __builtin_amdgcn_mfma_f32_16x16x32_bf16(e0, b0, hw[t], 0, 0, 0);
                s8 b1_ = *(const s8*)&WgT[(t * 16 + l16) * 72 + 32 + quad * 8];
                hw[t] = __builtin_amdgcn_mfma_f32_16x16x32_bf16(e1, b1_, hw[t], 0, 0, 0);
            }
            #pragma unroll
            for (int t = 0; t < 4; t++) {
                int col = t * 16 + l16;
                float alv = al[col], arv = ar[col];
                #pragma unroll
                for (int r = 0; r < 4; r++) {
                    int row = row0 + quad * 4 + r;
                    float h = hw[t][r];
                    P[(size_t)row * 64 + col] = bf16r(h) | ((unsigned)vb[t][r] << 16);
                    float pl = h * alv, pr = h * arv;
                    #pragma unroll
                    for (int m = 1; m < 16; m <<= 1) {
                        pl += __shfl_xor(pl, m, 64);
                        pr += __shfl_xor(pr, m, 64);
                    }
                    if (l16 == 0) {
                        el[(size_t)row * 4 + t] = pl;
                        er[(size_t)row * 4 + t] = pr;
                    }
                }
            }
        }
    }
}

// ========== k_route: fp32 LDS-tiled gating, 64 nodes/block ==========
__global__ __launch_bounds__(256) void k_route(const float* __restrict__ zg,
        const float* __restrict__ zi,
        const float* __restrict__ ggW, const float* __restrict__ ggb,
        const float* __restrict__ igW, const float* __restrict__ igb,
        float* __restrict__ wgtg, float* __restrict__ wgti,
        float* __restrict__ stats) {
    __shared__ float zs[64][65];
    __shared__ float gws[256];
    __shared__ float sstat[16];
    if (threadIdx.x < 16) sstat[threadIdx.x] = 0.f;
    int n0 = blockIdx.x * 64;
    int wv = threadIdx.x >> 6, lane = threadIdx.x & 63;
    for (int q = 0; q < 2; q++) {
        const float* Z = q ? zi : zg;
        const float* GW = q ? igW : ggW;
        const float* GB = q ? igb : ggb;
        gws[threadIdx.x] = GW[threadIdx.x];
        #pragma unroll
        for (int r = 0; r < 16; r++) {
            int row = wv * 16 + r;
            int n = n0 + row;
            zs[row][lane] = (n < NN) ? Z[(size_t)n * 64 + lane] : 0.f;
        }
        __syncthreads();
        int node = threadIdx.x >> 2, e = threadIdx.x & 3;
        float lg = GB[e];
        #pragma unroll 8
        for (int k = 0; k < 64; k++) lg += zs[node][k] * gws[k * 4 + e];
        float b = __shfl_xor(lg, 1, 64);
        float c = __shfl_xor(lg, 2, 64);
        float d = __shfl_xor(b, 2, 64);
        float arr[4];
        arr[e] = lg; arr[e ^ 1] = b; arr[e ^ 2] = c; arr[e ^ 3] = d;
        int n = n0 + node;
        if (e == 0 && n < NN) {
            float mx = fmaxf(fmaxf(arr[0], arr[1]), fmaxf(arr[2], arr[3]));
            float ex0 = __expf(arr[0] - mx), ex1 = __expf(arr[1] - mx);
            float ex2 = __expf(arr[2] - mx), ex3 = __expf(arr[3] - mx);
            float inv = 1.0f / (ex0 + ex1 + ex2 + ex3);
            float pr[4] = {ex0 * inv, ex1 * inv, ex2 * inv, ex3 * inv};
            int i1 = 0; float v1 = pr[0];
            #pragma unroll
            for (int t = 1; t < 4; t++) if (pr[t] > v1) { v1 = pr[t]; i1 = t; }
            int i2 = -1; float v2 = -1.f;
            #pragma unroll
            for (int t = 0; t < 4; t++) if (t != i1 && pr[t] > v2) { v2 = pr[t]; i2 = t; }
            float wsum = v1 + v2;
            float wq[4] = {0.f, 0.f, 0.f, 0.f};
            wq[i1] = v1 / wsum; wq[i2] = v2 / wsum;
            float* WD = q ? wgti : wgtg;
            *reinterpret_cast<float4*>(WD + (size_t)n * 4) = float4{wq[0], wq[1], wq[2], wq[3]};
            #pragma unroll
            for (int t = 0; t < 4; t++) atomicAdd(&sstat[q * 8 + t], pr[t]);
            atomicAdd(&sstat[q * 8 + 4 + i1], 1.f);
            atomicAdd(&sstat[q * 8 + 4 + i2], 1.f);
        }
        __syncthreads();
    }
    if (threadIdx.x < 16) atomicAdd(&stats[threadIdx.x], sstat[threadIdx.x]);
}

// ======= dense-all experts (MFMA), both problems in one grid =======
__global__ __launch_bounds__(256) void k_expert(const unsigned short* __restrict__ Eb,
        const unsigned short* __restrict__ Fb,
        const float* __restrict__ g_eW1, const float* __restrict__ g_eb1,
        const float* __restrict__ g_eW2, const float* __restrict__ g_eb2,
        const float* __restrict__ i_eW1, const float* __restrict__ i_eb1,
        const float* __restrict__ i_eW2, const float* __restrict__ i_eb2,
        const float* __restrict__ wgtg, const float* __restrict__ wgti,
        float* __restrict__ moegf, float* __restrict__ moeif,
        unsigned short* __restrict__ ub) {
    __shared__ unsigned short w1t[4 * 32 * 72];
    __shared__ unsigned short w2t[4 * 64 * 40];
    __shared__ unsigned short y1s[4][16 * 40];
    int p = (blockIdx.x >= NBE) ? 1 : 0;
    int bb = blockIdx.x - p * NBE;
    const unsigned short* Ab = p ? Fb : Eb;
    const float* eW1 = p ? i_eW1 : g_eW1;
    const float* eb1 = p ? i_eb1 : g_eb1;
    const float* eW2 = p ? i_eW2 : g_eW2;
    const float* eb2 = p ? i_eb2 : g_eb2;
    const float* wgt = p ? wgti : wgtg;
    float* moef = p ? moeif : moegf;
    int qoff = p ? 64 : 0;
    for (int g = threadIdx.x; g < 8192; g += 256) {
        int e = g >> 11, rem = g & 2047;
        int k = rem >> 5, n = rem & 31;
        w1t[e * 2304 + n * 72 + k] = (unsigned short)bf16r(eW1[g]);
    }
    for (int g = threadIdx.x; g < 8192; g += 256) {
        int e = g >> 11, rem = g & 2047;
        int k = rem >> 6, n = rem & 63;
        w2t[e * 2560 + n * 40 + k] = (unsigned short)bf16r(eW2[g]);
    }
    __syncthreads();
    int wv = threadIdx.x >> 6, lane = threadIdx.x & 63;
    int quad = lane >> 4, l16 = lane & 15;
    int gw = bb * 4 + wv;
    int mtEnd = gw * 4 + 4; if (mtEnd > 3125) mtEnd = 3125;
    for (int mt = gw * 4; mt < mtEnd; mt++) {
        int row0 = mt * 16;
        const unsigned short* arow = Ab + (size_t)(row0 + l16) * 64;
        s8 a0 = *(const s8*)(arow + quad * 8);
        s8 a1 = *(const s8*)(arow + 32 + quad * 8);
        f4 outacc[4];
        #pragma unroll
        for (int t = 0; t < 4; t++) outacc[t] = f4{0.f,0.f,0.f,0.f};
        for (int e = 0; e < 4; e++) {
            f4 acc1[2];
            #pragma unroll
            for (int t = 0; t < 2; t++) {
                acc1[t] = f4{0.f,0.f,0.f,0.f};
                s8 b0 = *(const s8*)&w1t[e * 2304 + (t * 16 + l16) * 72 + quad * 8];
                acc1[t] = __builtin_amdgcn_mfma_f32_16x16x32_bf16(a0, b0, acc1[t], 0, 0, 0);
                s8 b1_ = *(const s8*)&w1t[e * 2304 + (t * 16 + l16) * 72 + 32 + quad * 8];
                acc1[t] = __builtin_amdgcn_mfma_f32_16x16x32_bf16(a1, b1_, acc1[t], 0, 0, 0);
            }
            #pragma unroll
            for (int t = 0; t < 2; t++) {
                float b1v = eb1[e * 32 + t * 16 + l16];
                #pragma unroll
                for (int r = 0; r < 4; r++) {
                    float v = fmaxf(acc1[t][r] + b1v, 0.f);
                    y1s[wv][(quad * 4 + r) * 40 + t * 16 + l16] = (unsigned short)bf16r(v);
                }
            }
            s8 a2 = *(const s8*)&y1s[wv][l16 * 40 + quad * 8];
            f4 acc2[4];
            #pragma unroll
            for (int t = 0; t < 4; t++) {
                acc2[t] = f4{0.f,0.f,0.f,0.f};
                s8 b2_ = *(const s8*)&w2t[e * 2560 + (t * 16 + l16) * 40 + quad * 8];
                acc2[t] = __builtin_amdgcn_mfma_f32_16x16x32_bf16(a2, b2_, acc2[t], 0, 0, 0);
            }
            #pragma unroll
            for (int t = 0; t < 4; t++) {
                float b2v = eb2[e * 64 + t * 16 + l16];
                #pragma unroll
                for (int r = 0; r < 4; r++) {
                    float we = wgt[(size_t)(row0 + quad * 4 + r) * 4 + e];
                    outacc[t][r] += we * (acc2[t][r] + b2v);
                }
            }
        }
        #pragma unroll
        for (int t = 0; t < 4; t++) {
            int col = t * 16 + l16;
            #pragma unroll
            for (int r = 0; r < 4; r++) {
                int row = row0 + quad * 4 + r;
                float v = outacc[t][r];
                moef[(size_t)row * 64 + col] = v;
                ub[(size_t)row * 128 + qoff + col] = (unsigned short)bf16r(v);
            }
        }
    }
}

// ================= fusion gate (MFMA) + aux finalize (block 0) =================
__global__ __launch_bounds__(256) void k_fusion(const unsigned short* __restrict__ ubuf,
        const float* __restrict__ W1, const float* __restrict__ b1,
        const float* __restrict__ W2, const float* __restrict__ b2,
        const float* __restrict__ moegf, const float* __restrict__ moeif,
        float* __restrict__ out, const float* __restrict__ stats) {
    __shared__ unsigned short W1T[64 * 136];
    __shared__ unsigned short W2T[64 * 72];
    __shared__ unsigned short y1s[4][16 * 72];
    for (int idx = threadIdx.x; idx < 128 * 64; idx += 256) {
        int k = idx >> 6, n = idx & 63;
        W1T[n * 136 + k] = (unsigned short)bf16r(W1[idx]);
    }
    for (int idx = threadIdx.x; idx < 64 * 64; idx += 256) {
        int k = idx >> 6, n = idx & 63;
        W2T[n * 72 + k] = (unsigned short)bf16r(W2[idx]);
    }
    __syncthreads();
    int wv = threadIdx.x >> 6, lane = threadIdx.x & 63;
    int quad = lane >> 4, l16 = lane & 15;
    int gw = blockIdx.x * 4 + wv;
    int mtEnd = gw * 2 + 2; if (mtEnd > 3125) mtEnd = 3125;
    for (int mt = gw * 2; mt < mtEnd; mt++) {
        int row0 = mt * 16;
        const unsigned short* arow = ubuf + (size_t)(row0 + l16) * 128;
        f4 acc1[4];
        #pragma unroll
        for (int t = 0; t < 4; t++) acc1[t] = f4{0.f,0.f,0.f,0.f};
        #pragma unroll
        for (int ks = 0; ks < 4; ks++) {
            s8 a = *(const s8*)(arow + ks * 32 + quad * 8);
            #pragma unroll
            for (int t = 0; t < 4; t++) {
                s8 b = *(const s8*)&W1T[(t * 16 + l16) * 136 + ks * 32 + quad * 8];
                acc1[t] = __builtin_amdgcn_mfma_f32_16x16x32_bf16(a, b, acc1[t], 0, 0, 0);
            }
        }
        #pragma unroll
        for (int t = 0; t < 4; t++) {
            float b1v = b1[t * 16 + l16];
            #pragma unroll
            for (int r = 0; r < 4; r++) {
                float v = fmaxf(acc1[t][r] + b1v, 0.f);
                y1s[wv][(quad * 4 + r) * 72 + t * 16 + l16] = (unsigned short)bf16r(v);
            }
        }
        f4 acc2[4];
        #pragma unroll
        for (int t = 0; t < 4; t++) acc2[t] = f4{0.f,0.f,0.f,0.f};
        #pragma unroll
        for (int ks = 0; ks < 2; ks++) {
            s8 a = *(const s8*)&y1s[wv][l16 * 72 + ks * 32 + quad * 8];
            #pragma unroll
            for (int t = 0; t < 4; t++) {
                s8 b = *(const s8*)&W2T[(t * 16 + l16) * 72 + ks * 32 + quad * 8];
                acc2[t] = __builtin_amdgcn_mfma_f32_16x16x32_bf16(a, b, acc2[t], 0, 0, 0);
            }
        }
        #pragma unroll
        for (int t = 0; t < 4; t++) {
            int col = t * 16 + l16;
            float b2v = b2[col];
            #pragma unroll
            for (int r = 0; r < 4; r++) {
                int row = row0 + quad * 4 + r;
                float g = 1.0f / (1.0f + __expf(-(acc2[t][r] + b2v)));
                float zgv = moegf[(size_t)row * 64 + col];
                float ziv = moeif[(size_t)row * 64 + col];
                out[(size_t)row * 64 + col] = g * zgv * ziv + (1.0f - g) * g;
            }
        }
    }
    if (blockIdx.x == 0 && threadIdx.x < 64) {
        int t = threadIdx.x;
        float s = (t < 16) ? stats[t] : 0.f;
        float aux = 0.f;
        for (int q = 0; q < 2; q++) {
            float a = 0.f;
            for (int e = 0; e < 4; e++) {
                float pr = __shfl(s, q * 8 + e, 64);
                float f  = __shfl(s, q * 8 + 4 + e, 64);
                a += (f / (float)NN) * (pr / (float)NN);
            }
            aux += 4.0f * a;
        }
        if (t == 0) out[(size_t)NN * 64] = aux;
    }
}

extern "C" void kernel_launch(void* const* d_in, const int* in_sizes, int n_in,
                              void* d_out, int out_size, void* d_ws, size_t ws_size,
                              hipStream_t stream) {
    (void)in_sizes; (void)n_in; (void)out_size; (void)ws_size;
    const float* features  = (const float*)d_in[0];
    const int*   node_types= (const int*)d_in[1];
    const int*   src       = (const int*)d_in[2];
    const int*   dst       = (const int*)d_in[3];
    const float* W_person  = (const float*)d_in[4];
    const float* b_person  = (const float*)d_in[5];
    const float* W_disease = (const float*)d_in[6];
    const float* b_disease = (const float*)d_in[7];
    const float* gat_W     = (const float*)d_in[8];
    const float* gat_al    = (const float*)d_in[9];
    const float* gat_ar    = (const float*)d_in[10];
    const float* gin_eps   = (const float*)d_in[11];
    const float* gin_W1    = (const float*)d_in[12];
    const float* gin_b1    = (const float*)d_in[13];
    const float* gin_W2    = (const float*)d_in[14];
    const float* gin_b2    = (const float*)d_in[15];
    const float* gat_gW    = (const float*)d_in[16];
    const float* gat_gb    = (const float*)d_in[17];
    const float* gat_eW1   = (const float*)d_in[18];
    const float* gat_eb1   = (const float*)d_in[19];
    const float* gat_eW2   = (const float*)d_in[20];
    const float* gat_eb2   = (const float*)d_in[21];
    const float* gin_gW    = (const float*)d_in[22];
    const float* gin_gb    = (const float*)d_in[23];
    const float* gin_eW1   = (const float*)d_in[24];
    const float* gin_eb1   = (const float*)d_in[25];
    const float* gin_eW2   = (const float*)d_in[26];
    const float* gin_eb2   = (const float*)d_in[27];
    const float* fg_W1     = (const float*)d_in[28];
    const float* fg_b1     = (const float*)d_in[29];
    const float* fg_W2     = (const float*)d_in[30];
    const float* fg_b2     = (const float*)d_in[31];
    float* out = (float*)d_out;

    float* ws = (float*)d_ws;
    size_t o = 0;
    float* A = ws + o; o += (size_t)NN * 64;        // h0f; later ub (bf16 NN x 128)
    float* B = ws + o; o += (size_t)NN * 64;        // vg f32 chain; later moegf
    float* C = ws + o; o += (size_t)NN * 64;        // gin f32 chain; later moeif
    unsigned short* E  = (unsigned short*)(ws + o); o += (size_t)NN * 32;  // vgb
    unsigned short* F  = (unsigned short*)(ws + o); o += (size_t)NN * 32;  // ginb
    unsigned short* G  = (unsigned short*)(ws + o); o += (size_t)NN * 32;  // xb
    unsigned* P = (unsigned*)(ws + o); o += (size_t)NN * 64;  // packed hW|gin
    float* el = ws + o; o += (size_t)NN * 4;
    float* er = ws + o; o += (size_t)NN * 4;
    float* wgtg = ws + o; o += (size_t)NN * 4;
    float* wgti = ws + o; o += (size_t)NN * 4;
    // zeroed region: degcnt | bktcnt | stats (single memset)
    int* degcnt    = (int*)(ws + o); o += NN;
    int* bktcnt    = (int*)(ws + o); o += NBKT;
    float* stats   = ws + o; o += 16;
    int* row_start = (int*)(ws + o); o += NN + 4;
    int* bsums     = (int*)(ws + o); o += 256;
    int* bpre      = (int*)(ws + o); o += 256;
    int* csr_src   = (int*)(ws + o); o += EE;
    unsigned* bkt  = (unsigned*)(ws + o); o += (size_t)NBKT * BCAP;

    unsigned short* ub = (unsigned short*)A;  // reuse after edges(l0)

    const int NB_node = NN / 4;     // 12500

    hipMemsetAsync(degcnt, 0, sizeof(int) * (NN + NBKT) + sizeof(float) * 16, stream);

    // CSR build: bin pass (+degcnt), scans
    k_binA<<<NBINA, 256, 0, stream>>>(src, dst, degcnt, bktcnt, bkt);
    k_scan_a<<<NBLK_SCAN, 256, 0, stream>>>(degcnt, bsums);
    k_scan_b<<<1, 256, 0, stream>>>(bsums, bpre);
    k_scan_c<<<NBLK_SCAN, 256, 0, stream>>>(degcnt, bpre, row_start);

    // fused: CSR fill (blocks 0..97) + projection/GAT-l0 pre (blocks 98..)
    k_binB_pre<<<NBKT + NBG, 256, 0, stream>>>(row_start, bktcnt, bkt, csr_src,
                                               features, node_types, W_person, b_person,
                                               W_disease, b_disease, gat_W, gat_al, gat_ar,
                                               A, P, el, er);

    // ---- layer 0 ----
    k_edges<1><<<NB_node, 256, 0, stream>>>(row_start, csr_src, P, el, er, A, A,
                                            gin_eps, B, E, G);
    k_mlp<0><<<NBG, 256, 0, stream>>>(G, E, gin_W1, gin_b1, gin_W2, gin_b2,
                                      gat_W + 4096, gat_al + 64, gat_ar + 64,
                                      F, C, P, el, er);

    // ---- layer 1 ----
    k_edges<0><<<NB_node, 256, 0, stream>>>(row_start, csr_src, P, el, er, B, C,
                                            gin_eps + 1, B, E, G);
    k_mlp<1><<<NBG, 256, 0, stream>>>(G, nullptr, gin_W1 + 4096, gin_b1 + 64,
                                      gin_W2 + 4096, gin_b2 + 64,
                                      nullptr, nullptr, nullptr,
                                      F, C, nullptr, nullptr, nullptr);

    // ---- MoE: routing (fp32) + dense-all experts ----
    k_route<<<RBLK, 256, 0, stream>>>(B, C, gat_gW, gat_gb, gin_gW, gin_gb,
                                      wgtg, wgti, stats);
    k_expert<<<NBE * 2, 256, 0, stream>>>(E, F,
                                          gat_eW1, gat_eb1, gat_eW2, gat_eb2,
                                          gin_eW1, gin_eb1, gin_eW2, gin_eb2,
                                          wgtg, wgti, B, C, ub);

    // ---- fusion + aux ----
    k_fusion<<<NBG, 256, 0, stream>>>(ub, fg_W1, fg_b1, fg_W2, fg_b2, B, C, out, stats);
}